// Round 3
// baseline (1360.853 us; speedup 1.0000x reference)
//
#include <hip/hip_runtime.h>
#include <hip/hip_bf16.h>

#define NN 100000
#define NE 1600000
#define NT (NE + NN)
#define FIN 128
#define HID 64
#define NG 128
#define NC 10

typedef __hip_bfloat16 bf16;

// runtime-dtype float load: f32flag ? float32 : bf16
__device__ __forceinline__ float ldx(const void* p, size_t i, int f32flag) {
    return f32flag ? ((const float*)p)[i]
                   : __bfloat162float(((const bf16*)p)[i]);
}

// ---------------- dtype probe ----------------
__global__ void probe_kernel(const unsigned int* __restrict__ xw,
                             const int* __restrict__ ei,
                             int* __restrict__ flags) {
    if (threadIdx.x != 0 || blockIdx.x != 0) return;
    int f32 = 0;
    for (int i = 0; i < 64; i++) {
        unsigned int u = xw[i];
        unsigned int lo = (u & 0xffffu) << 16;
        unsigned int hi = u & 0xffff0000u;
        float vl = __uint_as_float(lo);
        float vh = __uint_as_float(hi);
        if (!(fabsf(vl) < 1e10f)) f32 = 1;   // NaN or huge -> underlying f32
        if (!(fabsf(vh) < 1e10f)) f32 = 1;
    }
    int i64 = 1;
    for (int i = 0; i < 64; i++)
        if (ei[2 * i + 1] != 0) i64 = 0;     // high words all zero -> int64
    flags[0] = f32;
    flags[1] = i64;
}

// ---------------- param conversion into f32 block ----------------
__global__ __launch_bounds__(256) void cparams_kernel(
        const void* p0, const void* p1, const void* p2, const void* p3,
        const void* p4, const void* p5, const void* p6, const void* p7,
        const void* p8, const void* p9, const void* p10, const void* p11,
        const int* __restrict__ flags, float* __restrict__ Pf) {
    const void* ps[12] = {p0,p1,p2,p3,p4,p5,p6,p7,p8,p9,p10,p11};
    const int   sz[12] = {8192,64,64,64,4096,64,64,64,2048,32,320,10};
    const int f = flags[0];
    int off = 0;
    for (int t = 0; t < 12; t++) {
        for (int i = threadIdx.x; i < sz[t]; i += 256)
            Pf[off + i] = ldx(ps[t], i, f);
        off += sz[t];
    }
}

// ---------------- GEMM: H[N,HID] = X[N,K] @ W[K,HID] ----------------
template <int K>
__global__ __launch_bounds__(256) void gemm_kernel(const void* __restrict__ X,
                                                   const float* __restrict__ Wf,
                                                   float* __restrict__ H,
                                                   const int* __restrict__ flags,
                                                   int force_f32) {
    __shared__ float Wl[K * HID];
    __shared__ float Xl[16 * K];
    const int t = threadIdx.x;
    const int f = force_f32 ? 1 : flags[0];
    for (int i = t; i < K * HID; i += 256) Wl[i] = Wf[i];
    const size_t base = (size_t)blockIdx.x * 16 * K;
    for (int i = t; i < 16 * K; i += 256) Xl[i] = ldx(X, base + i, f);
    __syncthreads();
    const int r = t >> 4;
    const int c4 = (t & 15) * 4;
    const float* xr = &Xl[r * K];
    const float* wp = &Wl[c4];
    float a0 = 0.f, a1 = 0.f, a2 = 0.f, a3 = 0.f;
#pragma unroll 4
    for (int k = 0; k < K; k++) {
        float xv = xr[k];
        float4 w4 = *(const float4*)(wp + k * HID);
        a0 += xv * w4.x; a1 += xv * w4.y; a2 += xv * w4.z; a3 += xv * w4.w;
    }
    float4 o; o.x = a0; o.y = a1; o.z = a2; o.w = a3;
    *(float4*)&H[((size_t)blockIdx.x * 16 + r) * HID + c4] = o;
}

// ---------------- alpha: AS[i] = H[i,:]·va, AD[i] = H[i,:]·vb ----------------
__global__ __launch_bounds__(256) void alpha_kernel(const float* __restrict__ H,
                                                    const float* __restrict__ va,
                                                    const float* __restrict__ vb,
                                                    float* __restrict__ AS,
                                                    float* __restrict__ AD) {
    int wid = (blockIdx.x * 256 + threadIdx.x) >> 6;
    int lane = threadIdx.x & 63;
    if (wid >= NN) return;
    float h = H[(size_t)wid * HID + lane];
    float s1 = h * va[lane];
    float s2 = h * vb[lane];
#pragma unroll
    for (int off = 32; off; off >>= 1) {
        s1 += __shfl_xor(s1, off);
        s2 += __shfl_xor(s2, off);
    }
    if (lane == 0) { AS[wid] = s1; AD[wid] = s2; }
}

// ---------------- CSR build ----------------
__global__ __launch_bounds__(256) void hist_kernel(const int* __restrict__ ei,
                                                   const int* __restrict__ flags,
                                                   int* __restrict__ cnt) {
    int e = blockIdx.x * 256 + threadIdx.x;
    if (e >= NT) return;
    const int i64 = flags[1];
    int d;
    if (e < NE) {
        long idx = (long)NE + e;                 // dst row
        d = i64 ? ei[2 * idx] : ei[idx];
    } else d = e - NE;
    if ((unsigned)d >= NN) d = 0;
    atomicAdd(&cnt[d], 1);
}

// scan + zero cnt afterwards (cnt reused as scatter cursor)
__global__ __launch_bounds__(1024) void scan_kernel(int* __restrict__ cnt,
                                                    int* __restrict__ rowptr) {
    __shared__ int sdata[1024];
    __shared__ int carry;
    const int t = threadIdx.x;
    if (t == 0) carry = 0;
    __syncthreads();
    for (int base = 0; base < NN; base += 1024) {
        int i = base + t;
        int v = (i < NN) ? cnt[i] : 0;
        sdata[t] = v;
        __syncthreads();
        for (int off = 1; off < 1024; off <<= 1) {
            int tmp = (t >= off) ? sdata[t - off] : 0;
            __syncthreads();
            sdata[t] += tmp;
            __syncthreads();
        }
        if (i < NN) { rowptr[i] = carry + sdata[t] - v; cnt[i] = 0; }
        __syncthreads();
        if (t == 1023) carry += sdata[1023];
        __syncthreads();
    }
    if (t == 0) rowptr[NN] = carry;
}

__global__ __launch_bounds__(256) void scatter_kernel(const int* __restrict__ ei,
                                                      const int* __restrict__ flags,
                                                      const int* __restrict__ rowptr,
                                                      int* __restrict__ cursor,
                                                      int* __restrict__ slot) {
    int e = blockIdx.x * 256 + threadIdx.x;
    if (e >= NT) return;
    const int i64 = flags[1];
    int s, d;
    if (e < NE) {
        s = i64 ? ei[2 * (long)e] : ei[e];
        long idx = (long)NE + e;
        d = i64 ? ei[2 * idx] : ei[idx];
    } else s = d = e - NE;
    if ((unsigned)d >= NN) d = 0;
    if ((unsigned)s >= NN) s = 0;
    int pos = atomicAdd(&cursor[d], 1);
    slot[rowptr[d] + pos] = s;
}

// ---------------- fused GAT edge phase: one wave per destination ----------------
__global__ __launch_bounds__(256) void edge_kernel(const float* __restrict__ H,
                                                   const float* __restrict__ AS,
                                                   const float* __restrict__ AD,
                                                   const int* __restrict__ rowptr,
                                                   const int* __restrict__ slot,
                                                   const float* __restrict__ bias,
                                                   float* __restrict__ OUT,
                                                   int relu_flag) {
    int wid = (blockIdx.x * 256 + threadIdx.x) >> 6;
    int lane = threadIdx.x & 63;
    if (wid >= NN) return;
    const int beg = rowptr[wid], end = rowptr[wid + 1];
    const float ad = AD[wid];
    float m = -1e30f;
    for (int j = beg + lane; j < end; j += 64) {
        int s = slot[j];
        float e = AS[s] + ad;
        e = e > 0.f ? e : 0.2f * e;
        m = fmaxf(m, e);
    }
#pragma unroll
    for (int off = 32; off; off >>= 1) m = fmaxf(m, __shfl_xor(m, off));
    float acc = 0.f, dsum = 0.f;
    for (int cbeg = beg; cbeg < end; cbeg += 64) {
        int j = cbeg + lane;
        float wv = 0.f;
        int s = 0;
        if (j < end) {
            s = slot[j];
            float e = AS[s] + ad;
            e = e > 0.f ? e : 0.2f * e;
            wv = __expf(e - m);
            dsum += wv;
        }
        int cn = min(64, end - cbeg);
        for (int u = 0; u < cn; ++u) {
            float wj = __shfl(wv, u);
            int sj = __shfl(s, u);
            acc += wj * H[(size_t)sj * HID + lane];
        }
    }
#pragma unroll
    for (int off = 32; off; off >>= 1) dsum += __shfl_xor(dsum, off);
    float o = acc / dsum + bias[lane];
    if (relu_flag) o = fmaxf(o, 0.f);
    OUT[(size_t)wid * HID + lane] = o;
}

// ---------------- mean pool (atomic) ----------------
__global__ __launch_bounds__(256) void pool_kernel(const float* __restrict__ O,
                                                   const int* __restrict__ bat,
                                                   const int* __restrict__ flags,
                                                   float* __restrict__ pooled,
                                                   int* __restrict__ counts) {
    int wid = (blockIdx.x * 256 + threadIdx.x) >> 6;
    int lane = threadIdx.x & 63;
    if (wid >= NN) return;
    const int i64 = flags[1];
    int b = i64 ? bat[2 * (long)wid] : bat[wid];
    if ((unsigned)b >= NG) b = 0;
    atomicAdd(&pooled[b * HID + lane], O[(size_t)wid * HID + lane]);
    if (lane == 0) atomicAdd(&counts[b], 1);
}

// ---------------- head (float32 output!) ----------------
__global__ __launch_bounds__(128) void head_kernel(const float* __restrict__ pooled,
                                                   const int* __restrict__ counts,
                                                   const float* __restrict__ lw, const float* __restrict__ lb,
                                                   const float* __restrict__ cw, const float* __restrict__ cb,
                                                   float* __restrict__ out) {
    int g = threadIdx.x;
    if (g >= NG) return;
    float inv = 1.f / fmaxf((float)counts[g], 1.f);
    float p[HID];
#pragma unroll
    for (int k = 0; k < HID; k++) p[k] = pooled[g * HID + k] * inv;
    float z[32];
#pragma unroll
    for (int j = 0; j < 32; j++) {
        float acc = lb[j];
#pragma unroll
        for (int k = 0; k < HID; k++) acc += p[k] * lw[k * 32 + j];
        z[j] = fmaxf(acc, 0.f);
    }
    float lg[NC];
    float mx = -1e30f;
#pragma unroll
    for (int c = 0; c < NC; c++) {
        float acc = cb[c];
#pragma unroll
        for (int j = 0; j < 32; j++) acc += z[j] * cw[j * NC + c];
        lg[c] = acc;
        mx = fmaxf(mx, acc);
    }
    float s = 0.f;
#pragma unroll
    for (int c = 0; c < NC; c++) s += __expf(lg[c] - mx);
    float lse = mx + __logf(s);
#pragma unroll
    for (int c = 0; c < NC; c++) out[g * NC + c] = lg[c] - lse;
}

extern "C" void kernel_launch(void* const* d_in, const int* in_sizes, int n_in,
                              void* d_out, int out_size, void* d_ws, size_t ws_size,
                              hipStream_t stream) {
    const void* x   = d_in[0];
    const int*  ei  = (const int*)d_in[1];
    // d_in[2] edge_weight: unused (GATConv has no lin_edge)
    const int*  bat = (const int*)d_in[3];

    char* w = (char*)d_ws;
    float* H      = (float*)w; w += sizeof(float) * NN * HID;
    float* O      = (float*)w; w += sizeof(float) * NN * HID;
    float* AS     = (float*)w; w += sizeof(float) * NN;
    float* AD     = (float*)w; w += sizeof(float) * NN;
    int* cnt      = (int*)w;   w += sizeof(int) * (NN + 1);   // reused as cursor
    int* rowptr   = (int*)w;   w += sizeof(int) * (NN + 1);
    int* slot     = (int*)w;   w += sizeof(int) * NT;
    float* pooled = (float*)w; w += sizeof(float) * NG * HID;
    int* counts   = (int*)w;   w += sizeof(int) * NG;
    int* flags    = (int*)w;   w += sizeof(int) * 2;
    float* Pf     = (float*)w; w += sizeof(float) * 16384;

    // Pf offsets
    float* W1f = Pf;             float* as1 = Pf + 8192;
    float* ad1 = Pf + 8256;      float* b1  = Pf + 8320;
    float* W2f = Pf + 8384;      float* as2 = Pf + 12480;
    float* ad2 = Pf + 12544;     float* b2  = Pf + 12608;
    float* lw  = Pf + 12672;     float* lb  = Pf + 14720;
    float* cw  = Pf + 14752;     float* cb  = Pf + 15072;

    hipMemsetAsync(cnt, 0, sizeof(int) * (NN + 1), stream);
    hipMemsetAsync(pooled, 0, sizeof(float) * NG * HID + sizeof(int) * NG, stream);

    probe_kernel<<<1, 64, 0, stream>>>((const unsigned int*)x, ei, flags);
    cparams_kernel<<<1, 256, 0, stream>>>(d_in[4], d_in[5], d_in[6], d_in[7],
                                          d_in[8], d_in[9], d_in[10], d_in[11],
                                          d_in[12], d_in[13], d_in[14], d_in[15],
                                          flags, Pf);
    gemm_kernel<FIN><<<NN / 16, 256, 0, stream>>>(x, W1f, H, flags, 0);
    alpha_kernel<<<NN / 4, 256, 0, stream>>>(H, as1, ad1, AS, AD);
    hist_kernel<<<(NT + 255) / 256, 256, 0, stream>>>(ei, flags, cnt);
    scan_kernel<<<1, 1024, 0, stream>>>(cnt, rowptr);
    scatter_kernel<<<(NT + 255) / 256, 256, 0, stream>>>(ei, flags, rowptr, cnt, slot);
    edge_kernel<<<NN / 4, 256, 0, stream>>>(H, AS, AD, rowptr, slot, b1, O, 1);
    gemm_kernel<HID><<<NN / 16, 256, 0, stream>>>(O, W2f, H, flags, 1);
    alpha_kernel<<<NN / 4, 256, 0, stream>>>(H, as2, ad2, AS, AD);
    edge_kernel<<<NN / 4, 256, 0, stream>>>(H, AS, AD, rowptr, slot, b2, O, 0);
    pool_kernel<<<NN / 4, 256, 0, stream>>>(O, bat, flags, pooled, counts);
    head_kernel<<<1, 128, 0, stream>>>(pooled, counts, lw, lb, cw, cb, (float*)d_out);
}

// Round 4
// 735.574 us; speedup vs baseline: 1.8501x; 1.8501x over previous
//
#include <hip/hip_runtime.h>
#include <hip/hip_bf16.h>

#define NN 100000
#define NE 1600000
#define NT (NE + NN)
#define FIN 128
#define HID 64
#define NG 128
#define NC 10
#define SCAN_B 1024
#define SCAN_NBLK ((NN + SCAN_B - 1) / SCAN_B)   // 98

typedef __hip_bfloat16 bf16;

// runtime-dtype float load: f32flag ? float32 : bf16
__device__ __forceinline__ float ldx(const void* p, size_t i, int f32flag) {
    return f32flag ? ((const float*)p)[i]
                   : __bfloat162float(((const bf16*)p)[i]);
}

// ---------------- dtype probe ----------------
__global__ void probe_kernel(const unsigned int* __restrict__ xw,
                             const int* __restrict__ ei,
                             int* __restrict__ flags) {
    if (threadIdx.x != 0 || blockIdx.x != 0) return;
    int f32 = 0;
    for (int i = 0; i < 64; i++) {
        unsigned int u = xw[i];
        unsigned int lo = (u & 0xffffu) << 16;
        unsigned int hi = u & 0xffff0000u;
        float vl = __uint_as_float(lo);
        float vh = __uint_as_float(hi);
        if (!(fabsf(vl) < 1e10f)) f32 = 1;   // NaN or huge -> underlying f32
        if (!(fabsf(vh) < 1e10f)) f32 = 1;
    }
    int i64 = 1;
    for (int i = 0; i < 64; i++)
        if (ei[2 * i + 1] != 0) i64 = 0;     // high words all zero -> int64
    flags[0] = f32;
    flags[1] = i64;
}

// ---------------- param conversion into f32 block ----------------
__global__ __launch_bounds__(256) void cparams_kernel(
        const void* p0, const void* p1, const void* p2, const void* p3,
        const void* p4, const void* p5, const void* p6, const void* p7,
        const void* p8, const void* p9, const void* p10, const void* p11,
        const int* __restrict__ flags, float* __restrict__ Pf) {
    const void* ps[12] = {p0,p1,p2,p3,p4,p5,p6,p7,p8,p9,p10,p11};
    const int   sz[12] = {8192,64,64,64,4096,64,64,64,2048,32,320,10};
    const int f = flags[0];
    int off = 0;
    for (int t = 0; t < 12; t++) {
        for (int i = threadIdx.x; i < sz[t]; i += 256)
            Pf[off + i] = ldx(ps[t], i, f);
        off += sz[t];
    }
}

// ---------------- GEMM: H[N,HID] = X[N,K] @ W[K,HID] ----------------
template <int K>
__global__ __launch_bounds__(256) void gemm_kernel(const void* __restrict__ X,
                                                   const float* __restrict__ Wf,
                                                   float* __restrict__ H,
                                                   const int* __restrict__ flags,
                                                   int force_f32) {
    __shared__ float Wl[K * HID];
    __shared__ float Xl[16 * K];
    const int t = threadIdx.x;
    const int f = force_f32 ? 1 : flags[0];
    for (int i = t; i < K * HID; i += 256) Wl[i] = Wf[i];
    const size_t base = (size_t)blockIdx.x * 16 * K;
    for (int i = t; i < 16 * K; i += 256) Xl[i] = ldx(X, base + i, f);
    __syncthreads();
    const int r = t >> 4;
    const int c4 = (t & 15) * 4;
    const float* xr = &Xl[r * K];
    const float* wp = &Wl[c4];
    float a0 = 0.f, a1 = 0.f, a2 = 0.f, a3 = 0.f;
#pragma unroll 4
    for (int k = 0; k < K; k++) {
        float xv = xr[k];
        float4 w4 = *(const float4*)(wp + k * HID);
        a0 += xv * w4.x; a1 += xv * w4.y; a2 += xv * w4.z; a3 += xv * w4.w;
    }
    float4 o; o.x = a0; o.y = a1; o.z = a2; o.w = a3;
    *(float4*)&H[((size_t)blockIdx.x * 16 + r) * HID + c4] = o;
}

// ---------------- alpha: AS[i] = H[i,:]·va, AD[i] = H[i,:]·vb ----------------
__global__ __launch_bounds__(256) void alpha_kernel(const float* __restrict__ H,
                                                    const float* __restrict__ va,
                                                    const float* __restrict__ vb,
                                                    float* __restrict__ AS,
                                                    float* __restrict__ AD) {
    int wid = (blockIdx.x * 256 + threadIdx.x) >> 6;
    int lane = threadIdx.x & 63;
    if (wid >= NN) return;
    float h = H[(size_t)wid * HID + lane];
    float s1 = h * va[lane];
    float s2 = h * vb[lane];
#pragma unroll
    for (int off = 32; off; off >>= 1) {
        s1 += __shfl_xor(s1, off);
        s2 += __shfl_xor(s2, off);
    }
    if (lane == 0) { AS[wid] = s1; AD[wid] = s2; }
}

// ---------------- CSR build ----------------
__global__ __launch_bounds__(256) void hist_kernel(const int* __restrict__ ei,
                                                   const int* __restrict__ flags,
                                                   int* __restrict__ cnt) {
    int e = blockIdx.x * 256 + threadIdx.x;
    if (e >= NT) return;
    const int i64 = flags[1];
    int d;
    if (e < NE) {
        long idx = (long)NE + e;                 // dst row
        d = i64 ? ei[2 * idx] : ei[idx];
    } else d = e - NE;
    if ((unsigned)d >= NN) d = 0;
    atomicAdd(&cnt[d], 1);
}

// hierarchical exclusive scan of cnt -> rowptr (3 kernels)
__global__ __launch_bounds__(1024) void scanA_kernel(const int* __restrict__ cnt,
                                                     int* __restrict__ rowptr,
                                                     int* __restrict__ bsum) {
    const int b = blockIdx.x, t = threadIdx.x;
    const int i = b * SCAN_B + t;
    const int lane = t & 63, wv = t >> 6;
    int v = (i < NN) ? cnt[i] : 0;
    int x = v;
#pragma unroll
    for (int off = 1; off < 64; off <<= 1) {
        int y = __shfl_up(x, off);
        if (lane >= off) x += y;
    }
    __shared__ int wsum[16];
    if (lane == 63) wsum[wv] = x;
    __syncthreads();
    if (wv == 0 && lane < 16) {
        int s = wsum[lane];
#pragma unroll
        for (int off = 1; off < 16; off <<= 1) {
            int y = __shfl_up(s, off);
            if (lane >= off) s += y;
        }
        wsum[lane] = s;
    }
    __syncthreads();
    int incl = x + (wv > 0 ? wsum[wv - 1] : 0);
    if (i < NN) rowptr[i + 1] = incl;          // block-local; offset added in scanC
    if (t == SCAN_B - 1) bsum[b] = incl;
}

__global__ __launch_bounds__(128) void scanB_kernel(const int* __restrict__ bsum,
                                                    int* __restrict__ boff,
                                                    int* __restrict__ rowptr) {
    const int t = threadIdx.x;
    const int lane = t & 63, wv = t >> 6;
    int v = (t < SCAN_NBLK) ? bsum[t] : 0;
    int x = v;
#pragma unroll
    for (int off = 1; off < 64; off <<= 1) {
        int y = __shfl_up(x, off);
        if (lane >= off) x += y;
    }
    __shared__ int w0;
    if (wv == 0 && lane == 63) w0 = x;
    __syncthreads();
    int incl = x + (wv == 1 ? w0 : 0);
    if (t < SCAN_NBLK) boff[t] = incl - v;     // exclusive block offsets
    if (t == 0) rowptr[0] = 0;
}

__global__ __launch_bounds__(1024) void scanC_kernel(int* __restrict__ rowptr,
                                                     const int* __restrict__ boff,
                                                     int* __restrict__ cnt) {
    const int i = blockIdx.x * SCAN_B + threadIdx.x;
    if (i < NN) {
        rowptr[i + 1] += boff[blockIdx.x];
        cnt[i] = 0;                            // cnt reused as scatter cursor
    }
}

__global__ __launch_bounds__(256) void scatter_kernel(const int* __restrict__ ei,
                                                      const int* __restrict__ flags,
                                                      const int* __restrict__ rowptr,
                                                      int* __restrict__ cursor,
                                                      int* __restrict__ slot) {
    int e = blockIdx.x * 256 + threadIdx.x;
    if (e >= NT) return;
    const int i64 = flags[1];
    int s, d;
    if (e < NE) {
        s = i64 ? ei[2 * (long)e] : ei[e];
        long idx = (long)NE + e;
        d = i64 ? ei[2 * idx] : ei[idx];
    } else s = d = e - NE;
    if ((unsigned)d >= NN) d = 0;
    if ((unsigned)s >= NN) s = 0;
    int pos = atomicAdd(&cursor[d], 1);
    slot[rowptr[d] + pos] = s;
}

// ---------------- fused GAT edge phase: one wave per destination ----------------
__global__ __launch_bounds__(256) void edge_kernel(const float* __restrict__ H,
                                                   const float* __restrict__ AS,
                                                   const float* __restrict__ AD,
                                                   const int* __restrict__ rowptr,
                                                   const int* __restrict__ slot,
                                                   const float* __restrict__ bias,
                                                   float* __restrict__ OUT,
                                                   int relu_flag) {
    int wid = (blockIdx.x * 256 + threadIdx.x) >> 6;
    int lane = threadIdx.x & 63;
    if (wid >= NN) return;
    const int beg = rowptr[wid], end = rowptr[wid + 1];
    const float ad = AD[wid];
    float m = -1e30f;
    for (int j = beg + lane; j < end; j += 64) {
        int s = slot[j];
        float e = AS[s] + ad;
        e = e > 0.f ? e : 0.2f * e;
        m = fmaxf(m, e);
    }
#pragma unroll
    for (int off = 32; off; off >>= 1) m = fmaxf(m, __shfl_xor(m, off));
    float acc = 0.f, dsum = 0.f;
    for (int cbeg = beg; cbeg < end; cbeg += 64) {
        int j = cbeg + lane;
        float wv = 0.f;
        int s = 0;
        if (j < end) {
            s = slot[j];
            float e = AS[s] + ad;
            e = e > 0.f ? e : 0.2f * e;
            wv = __expf(e - m);
            dsum += wv;
        }
        int cn = min(64, end - cbeg);
        for (int u = 0; u < cn; ++u) {
            float wj = __shfl(wv, u);
            int sj = __shfl(s, u);
            acc += wj * H[(size_t)sj * HID + lane];
        }
    }
#pragma unroll
    for (int off = 32; off; off >>= 1) dsum += __shfl_xor(dsum, off);
    float o = acc / dsum + bias[lane];
    if (relu_flag) o = fmaxf(o, 0.f);
    OUT[(size_t)wid * HID + lane] = o;
}

// ---------------- pooling: graph bounds + per-graph block mean ----------------
__global__ __launch_bounds__(256) void bounds_kernel(const int* __restrict__ bat,
                                                     const int* __restrict__ flags,
                                                     int* __restrict__ gstart) {
    int g = threadIdx.x;
    if (g > NG) return;
    const int i64 = flags[1];
    int lo = 0, hi = NN;
    while (lo < hi) {                       // first i with bat[i] >= g
        int mid = (lo + hi) >> 1;
        int v = i64 ? bat[2 * (long)mid] : bat[mid];
        if (v < g) lo = mid + 1; else hi = mid;
    }
    gstart[g] = lo;
}

__global__ __launch_bounds__(256) void pool2_kernel(const float* __restrict__ O,
                                                    const int* __restrict__ gstart,
                                                    float* __restrict__ pooled) {
    const int g = blockIdx.x;
    const int lane = threadIdx.x & 63;
    const int wv = threadIdx.x >> 6;
    const int beg = gstart[g], end = gstart[g + 1];
    float acc = 0.f;
    for (int i = beg + wv; i < end; i += 4)
        acc += O[(size_t)i * HID + lane];
    __shared__ float red[4][64];
    red[wv][lane] = acc;
    __syncthreads();
    if (wv == 0) {
        float s = red[0][lane] + red[1][lane] + red[2][lane] + red[3][lane];
        float cntg = (float)(end - beg);
        pooled[g * HID + lane] = s / fmaxf(cntg, 1.f);   // fused mean
    }
}

// ---------------- head (f32 output) ----------------
__global__ __launch_bounds__(128) void head_kernel(const float* __restrict__ pooled,
                                                   const float* __restrict__ lw, const float* __restrict__ lb,
                                                   const float* __restrict__ cw, const float* __restrict__ cb,
                                                   float* __restrict__ out) {
    int g = threadIdx.x;
    if (g >= NG) return;
    float p[HID];
#pragma unroll
    for (int k = 0; k < HID; k++) p[k] = pooled[g * HID + k];
    float z[32];
#pragma unroll
    for (int j = 0; j < 32; j++) {
        float acc = lb[j];
#pragma unroll
        for (int k = 0; k < HID; k++) acc += p[k] * lw[k * 32 + j];
        z[j] = fmaxf(acc, 0.f);
    }
    float lg[NC];
    float mx = -1e30f;
#pragma unroll
    for (int c = 0; c < NC; c++) {
        float acc = cb[c];
#pragma unroll
        for (int j = 0; j < 32; j++) acc += z[j] * cw[j * NC + c];
        lg[c] = acc;
        mx = fmaxf(mx, acc);
    }
    float s = 0.f;
#pragma unroll
    for (int c = 0; c < NC; c++) s += __expf(lg[c] - mx);
    float lse = mx + __logf(s);
#pragma unroll
    for (int c = 0; c < NC; c++) out[g * NC + c] = lg[c] - lse;
}

extern "C" void kernel_launch(void* const* d_in, const int* in_sizes, int n_in,
                              void* d_out, int out_size, void* d_ws, size_t ws_size,
                              hipStream_t stream) {
    const void* x   = d_in[0];
    const int*  ei  = (const int*)d_in[1];
    // d_in[2] edge_weight: unused (GATConv has no lin_edge)
    const int*  bat = (const int*)d_in[3];

    char* w = (char*)d_ws;
    float* H      = (float*)w; w += sizeof(float) * NN * HID;
    float* O      = (float*)w; w += sizeof(float) * NN * HID;
    float* AS     = (float*)w; w += sizeof(float) * NN;
    float* AD     = (float*)w; w += sizeof(float) * NN;
    int* cnt      = (int*)w;   w += sizeof(int) * (NN + 1);   // reused as cursor
    int* rowptr   = (int*)w;   w += sizeof(int) * (NN + 1);
    int* slot     = (int*)w;   w += sizeof(int) * NT;
    float* pooled = (float*)w; w += sizeof(float) * NG * HID;
    int* gstart   = (int*)w;   w += sizeof(int) * (NG + 1);
    int* bsum     = (int*)w;   w += sizeof(int) * SCAN_NBLK;
    int* boff     = (int*)w;   w += sizeof(int) * SCAN_NBLK;
    int* flags    = (int*)w;   w += sizeof(int) * 2;
    float* Pf     = (float*)w; w += sizeof(float) * 16384;

    // Pf offsets
    float* W1f = Pf;             float* as1 = Pf + 8192;
    float* ad1 = Pf + 8256;      float* b1  = Pf + 8320;
    float* W2f = Pf + 8384;      float* as2 = Pf + 12480;
    float* ad2 = Pf + 12544;     float* b2  = Pf + 12608;
    float* lw  = Pf + 12672;     float* lb  = Pf + 14720;
    float* cw  = Pf + 14752;     float* cb  = Pf + 15072;

    hipMemsetAsync(cnt, 0, sizeof(int) * (NN + 1), stream);

    probe_kernel<<<1, 64, 0, stream>>>((const unsigned int*)x, ei, flags);
    cparams_kernel<<<1, 256, 0, stream>>>(d_in[4], d_in[5], d_in[6], d_in[7],
                                          d_in[8], d_in[9], d_in[10], d_in[11],
                                          d_in[12], d_in[13], d_in[14], d_in[15],
                                          flags, Pf);
    gemm_kernel<FIN><<<NN / 16, 256, 0, stream>>>(x, W1f, H, flags, 0);
    alpha_kernel<<<NN / 4, 256, 0, stream>>>(H, as1, ad1, AS, AD);
    hist_kernel<<<(NT + 255) / 256, 256, 0, stream>>>(ei, flags, cnt);
    scanA_kernel<<<SCAN_NBLK, SCAN_B, 0, stream>>>(cnt, rowptr, bsum);
    scanB_kernel<<<1, 128, 0, stream>>>(bsum, boff, rowptr);
    scanC_kernel<<<SCAN_NBLK, SCAN_B, 0, stream>>>(rowptr, boff, cnt);
    scatter_kernel<<<(NT + 255) / 256, 256, 0, stream>>>(ei, flags, rowptr, cnt, slot);
    edge_kernel<<<NN / 4, 256, 0, stream>>>(H, AS, AD, rowptr, slot, b1, O, 1);
    gemm_kernel<HID><<<NN / 16, 256, 0, stream>>>(O, W2f, H, flags, 1);
    alpha_kernel<<<NN / 4, 256, 0, stream>>>(H, as2, ad2, AS, AD);
    edge_kernel<<<NN / 4, 256, 0, stream>>>(H, AS, AD, rowptr, slot, b2, O, 0);
    bounds_kernel<<<1, 256, 0, stream>>>(bat, flags, gstart);
    pool2_kernel<<<NG, 256, 0, stream>>>(O, gstart, pooled);
    head_kernel<<<1, 128, 0, stream>>>(pooled, lw, lb, cw, cb, (float*)d_out);
}

// Round 5
// 614.114 us; speedup vs baseline: 2.2160x; 1.1978x over previous
//
#include <hip/hip_runtime.h>
#include <hip/hip_bf16.h>

#define NN 100000
#define NE 1600000
#define NT (NE + NN)
#define FIN 128
#define HID 64
#define NG 128
#define NC 10
#define SCAN_B 1024
#define SCAN_NBLK ((NN + SCAN_B - 1) / SCAN_B)   // 98

typedef __hip_bfloat16 bf16;

// runtime-dtype float load: f32flag ? float32 : bf16
__device__ __forceinline__ float ldx(const void* p, size_t i, int f32flag) {
    return f32flag ? ((const float*)p)[i]
                   : __bfloat162float(((const bf16*)p)[i]);
}

// ---------------- dtype probe ----------------
__global__ void probe_kernel(const unsigned int* __restrict__ xw,
                             const int* __restrict__ ei,
                             int* __restrict__ flags) {
    if (threadIdx.x != 0 || blockIdx.x != 0) return;
    int f32 = 0;
    for (int i = 0; i < 64; i++) {
        unsigned int u = xw[i];
        unsigned int lo = (u & 0xffffu) << 16;
        unsigned int hi = u & 0xffff0000u;
        float vl = __uint_as_float(lo);
        float vh = __uint_as_float(hi);
        if (!(fabsf(vl) < 1e10f)) f32 = 1;   // NaN or huge -> underlying f32
        if (!(fabsf(vh) < 1e10f)) f32 = 1;
    }
    int i64 = 1;
    for (int i = 0; i < 64; i++)
        if (ei[2 * i + 1] != 0) i64 = 0;     // high words all zero -> int64
    flags[0] = f32;
    flags[1] = i64;
}

// ---------------- param conversion into f32 block ----------------
__global__ __launch_bounds__(256) void cparams_kernel(
        const void* p0, const void* p1, const void* p2, const void* p3,
        const void* p4, const void* p5, const void* p6, const void* p7,
        const void* p8, const void* p9, const void* p10, const void* p11,
        const int* __restrict__ flags, float* __restrict__ Pf) {
    const void* ps[12] = {p0,p1,p2,p3,p4,p5,p6,p7,p8,p9,p10,p11};
    const int   sz[12] = {8192,64,64,64,4096,64,64,64,2048,32,320,10};
    const int f = flags[0];
    int off = 0;
    for (int t = 0; t < 12; t++) {
        for (int i = threadIdx.x; i < sz[t]; i += 256)
            Pf[off + i] = ldx(ps[t], i, f);
        off += sz[t];
    }
}

// ---------------- GEMM: H[N,HID] = X[N,K] @ W[K,HID] ----------------
template <int K>
__global__ __launch_bounds__(256) void gemm_kernel(const void* __restrict__ X,
                                                   const float* __restrict__ Wf,
                                                   float* __restrict__ H,
                                                   const int* __restrict__ flags,
                                                   int force_f32) {
    __shared__ float Wl[K * HID];
    __shared__ float Xl[16 * K];
    const int t = threadIdx.x;
    const int f = force_f32 ? 1 : flags[0];
    for (int i = t; i < K * HID; i += 256) Wl[i] = Wf[i];
    const size_t base = (size_t)blockIdx.x * 16 * K;
    for (int i = t; i < 16 * K; i += 256) Xl[i] = ldx(X, base + i, f);
    __syncthreads();
    const int r = t >> 4;
    const int c4 = (t & 15) * 4;
    const float* xr = &Xl[r * K];
    const float* wp = &Wl[c4];
    float a0 = 0.f, a1 = 0.f, a2 = 0.f, a3 = 0.f;
#pragma unroll 4
    for (int k = 0; k < K; k++) {
        float xv = xr[k];
        float4 w4 = *(const float4*)(wp + k * HID);
        a0 += xv * w4.x; a1 += xv * w4.y; a2 += xv * w4.z; a3 += xv * w4.w;
    }
    float4 o; o.x = a0; o.y = a1; o.z = a2; o.w = a3;
    *(float4*)&H[((size_t)blockIdx.x * 16 + r) * HID + c4] = o;
}

// ---------------- alpha: AS[i] = H[i,:]·va, AD[i] = H[i,:]·vb ----------------
__global__ __launch_bounds__(256) void alpha_kernel(const float* __restrict__ H,
                                                    const float* __restrict__ va,
                                                    const float* __restrict__ vb,
                                                    float* __restrict__ AS,
                                                    float* __restrict__ AD) {
    int wid = (blockIdx.x * 256 + threadIdx.x) >> 6;
    int lane = threadIdx.x & 63;
    if (wid >= NN) return;
    float h = H[(size_t)wid * HID + lane];
    float s1 = h * va[lane];
    float s2 = h * vb[lane];
#pragma unroll
    for (int off = 32; off; off >>= 1) {
        s1 += __shfl_xor(s1, off);
        s2 += __shfl_xor(s2, off);
    }
    if (lane == 0) { AS[wid] = s1; AD[wid] = s2; }
}

// ---------------- CSR build ----------------
__global__ __launch_bounds__(256) void hist_kernel(const int* __restrict__ ei,
                                                   const int* __restrict__ flags,
                                                   int* __restrict__ cnt) {
    int e = blockIdx.x * 256 + threadIdx.x;
    if (e >= NT) return;
    const int i64 = flags[1];
    int d;
    if (e < NE) {
        long idx = (long)NE + e;                 // dst row
        d = i64 ? ei[2 * idx] : ei[idx];
    } else d = e - NE;
    if ((unsigned)d >= NN) d = 0;
    atomicAdd(&cnt[d], 1);
}

// hierarchical exclusive scan of cnt -> rowptr (3 kernels)
__global__ __launch_bounds__(1024) void scanA_kernel(const int* __restrict__ cnt,
                                                     int* __restrict__ rowptr,
                                                     int* __restrict__ bsum) {
    const int b = blockIdx.x, t = threadIdx.x;
    const int i = b * SCAN_B + t;
    const int lane = t & 63, wv = t >> 6;
    int v = (i < NN) ? cnt[i] : 0;
    int x = v;
#pragma unroll
    for (int off = 1; off < 64; off <<= 1) {
        int y = __shfl_up(x, off);
        if (lane >= off) x += y;
    }
    __shared__ int wsum[16];
    if (lane == 63) wsum[wv] = x;
    __syncthreads();
    if (wv == 0 && lane < 16) {
        int s = wsum[lane];
#pragma unroll
        for (int off = 1; off < 16; off <<= 1) {
            int y = __shfl_up(s, off);
            if (lane >= off) s += y;
        }
        wsum[lane] = s;
    }
    __syncthreads();
    int incl = x + (wv > 0 ? wsum[wv - 1] : 0);
    if (i < NN) rowptr[i + 1] = incl;          // block-local; offset added in scanC
    if (t == SCAN_B - 1) bsum[b] = incl;
}

__global__ __launch_bounds__(128) void scanB_kernel(const int* __restrict__ bsum,
                                                    int* __restrict__ boff,
                                                    int* __restrict__ rowptr) {
    const int t = threadIdx.x;
    const int lane = t & 63, wv = t >> 6;
    int v = (t < SCAN_NBLK) ? bsum[t] : 0;
    int x = v;
#pragma unroll
    for (int off = 1; off < 64; off <<= 1) {
        int y = __shfl_up(x, off);
        if (lane >= off) x += y;
    }
    __shared__ int w0;
    if (wv == 0 && lane == 63) w0 = x;
    __syncthreads();
    int incl = x + (wv == 1 ? w0 : 0);
    if (t < SCAN_NBLK) boff[t] = incl - v;     // exclusive block offsets
    if (t == 0) rowptr[0] = 0;
}

__global__ __launch_bounds__(1024) void scanC_kernel(int* __restrict__ rowptr,
                                                     const int* __restrict__ boff,
                                                     int* __restrict__ cnt) {
    const int i = blockIdx.x * SCAN_B + threadIdx.x;
    if (i < NN) {
        rowptr[i + 1] += boff[blockIdx.x];
        cnt[i] = 0;                            // cnt reused as scatter cursor
    }
}

__global__ __launch_bounds__(256) void scatter_kernel(const int* __restrict__ ei,
                                                      const int* __restrict__ flags,
                                                      const int* __restrict__ rowptr,
                                                      int* __restrict__ cursor,
                                                      int* __restrict__ slot) {
    int e = blockIdx.x * 256 + threadIdx.x;
    if (e >= NT) return;
    const int i64 = flags[1];
    int s, d;
    if (e < NE) {
        s = i64 ? ei[2 * (long)e] : ei[e];
        long idx = (long)NE + e;
        d = i64 ? ei[2 * idx] : ei[idx];
    } else s = d = e - NE;
    if ((unsigned)d >= NN) d = 0;
    if ((unsigned)s >= NN) s = 0;
    int pos = atomicAdd(&cursor[d], 1);
    slot[rowptr[d] + pos] = s;
}

// ---------------- fused GAT edge phase: one wave per destination ----------------
__global__ __launch_bounds__(256) void edge_kernel(const float* __restrict__ H,
                                                   const float* __restrict__ AS,
                                                   const float* __restrict__ AD,
                                                   const int* __restrict__ rowptr,
                                                   const int* __restrict__ slot,
                                                   const float* __restrict__ bias,
                                                   float* __restrict__ OUT,
                                                   int relu_flag) {
    int wid = (blockIdx.x * 256 + threadIdx.x) >> 6;
    int lane = threadIdx.x & 63;
    if (wid >= NN) return;
    const int beg = rowptr[wid], end = rowptr[wid + 1];
    const float ad = AD[wid];
    float m = -1e30f;
    for (int j = beg + lane; j < end; j += 64) {
        int s = slot[j];
        float e = AS[s] + ad;
        e = e > 0.f ? e : 0.2f * e;
        m = fmaxf(m, e);
    }
#pragma unroll
    for (int off = 32; off; off >>= 1) m = fmaxf(m, __shfl_xor(m, off));
    float acc = 0.f, dsum = 0.f;
    for (int cbeg = beg; cbeg < end; cbeg += 64) {
        int j = cbeg + lane;
        float wv = 0.f;
        int s = 0;
        if (j < end) {
            s = slot[j];
            float e = AS[s] + ad;
            e = e > 0.f ? e : 0.2f * e;
            wv = __expf(e - m);
            dsum += wv;
        }
        int cn = min(64, end - cbeg);
        for (int u = 0; u < cn; ++u) {
            float wj = __shfl(wv, u);
            int sj = __shfl(s, u);
            acc += wj * H[(size_t)sj * HID + lane];
        }
    }
#pragma unroll
    for (int off = 32; off; off >>= 1) dsum += __shfl_xor(dsum, off);
    float o = acc / dsum + bias[lane];
    if (relu_flag) o = fmaxf(o, 0.f);
    OUT[(size_t)wid * HID + lane] = o;
}

// ---------------- pooling: graph bounds + per-graph block mean ----------------
__global__ __launch_bounds__(256) void bounds_kernel(const int* __restrict__ bat,
                                                     const int* __restrict__ flags,
                                                     int* __restrict__ gstart) {
    int g = threadIdx.x;
    if (g > NG) return;
    const int i64 = flags[1];
    int lo = 0, hi = NN;
    while (lo < hi) {                       // first i with bat[i] >= g
        int mid = (lo + hi) >> 1;
        int v = i64 ? bat[2 * (long)mid] : bat[mid];
        if (v < g) lo = mid + 1; else hi = mid;
    }
    gstart[g] = lo;
}

__global__ __launch_bounds__(256) void pool2_kernel(const float* __restrict__ O,
                                                    const int* __restrict__ gstart,
                                                    float* __restrict__ pooled) {
    const int g = blockIdx.x;
    const int lane = threadIdx.x & 63;
    const int wv = threadIdx.x >> 6;
    const int beg = gstart[g], end = gstart[g + 1];
    float acc = 0.f;
    for (int i = beg + wv; i < end; i += 4)
        acc += O[(size_t)i * HID + lane];
    __shared__ float red[4][64];
    red[wv][lane] = acc;
    __syncthreads();
    if (wv == 0) {
        float s = red[0][lane] + red[1][lane] + red[2][lane] + red[3][lane];
        float cntg = (float)(end - beg);
        pooled[g * HID + lane] = s / fmaxf(cntg, 1.f);   // fused mean
    }
}

// ---------------- head: one block per graph, LDS staging (no spills) ----------------
__global__ __launch_bounds__(64) void head_kernel(const float* __restrict__ pooled,
                                                  const float* __restrict__ lw, const float* __restrict__ lb,
                                                  const float* __restrict__ cw, const float* __restrict__ cb,
                                                  float* __restrict__ out) {
    const int g = blockIdx.x;
    const int t = threadIdx.x;
    __shared__ float p[HID];
    __shared__ float z[32];
    __shared__ float lg[NC];
    p[t] = pooled[g * HID + t];
    __syncthreads();
    if (t < 32) {
        float acc = lb[t];
#pragma unroll
        for (int k = 0; k < HID; k++) acc += p[k] * lw[k * 32 + t];
        z[t] = fmaxf(acc, 0.f);
    }
    __syncthreads();
    if (t < NC) {
        float acc = cb[t];
#pragma unroll
        for (int j = 0; j < 32; j++) acc += z[j] * cw[j * NC + t];
        lg[t] = acc;
    }
    __syncthreads();
    if (t < NC) {
        float mx = -1e30f;
#pragma unroll
        for (int c = 0; c < NC; c++) mx = fmaxf(mx, lg[c]);
        float s = 0.f;
#pragma unroll
        for (int c = 0; c < NC; c++) s += __expf(lg[c] - mx);
        out[g * NC + t] = lg[t] - mx - __logf(s);
    }
}

extern "C" void kernel_launch(void* const* d_in, const int* in_sizes, int n_in,
                              void* d_out, int out_size, void* d_ws, size_t ws_size,
                              hipStream_t stream) {
    const void* x   = d_in[0];
    const int*  ei  = (const int*)d_in[1];
    // d_in[2] edge_weight: unused (GATConv has no lin_edge)
    const int*  bat = (const int*)d_in[3];

    char* w = (char*)d_ws;
    float* H      = (float*)w; w += sizeof(float) * NN * HID;
    float* O      = (float*)w; w += sizeof(float) * NN * HID;
    float* AS     = (float*)w; w += sizeof(float) * NN;
    float* AD     = (float*)w; w += sizeof(float) * NN;
    int* cnt      = (int*)w;   w += sizeof(int) * (NN + 1);   // reused as cursor
    int* rowptr   = (int*)w;   w += sizeof(int) * (NN + 1);
    int* slot     = (int*)w;   w += sizeof(int) * NT;
    float* pooled = (float*)w; w += sizeof(float) * NG * HID;
    int* gstart   = (int*)w;   w += sizeof(int) * (NG + 1);
    int* bsum     = (int*)w;   w += sizeof(int) * SCAN_NBLK;
    int* boff     = (int*)w;   w += sizeof(int) * SCAN_NBLK;
    int* flags    = (int*)w;   w += sizeof(int) * 2;
    float* Pf     = (float*)w; w += sizeof(float) * 16384;

    // Pf offsets
    float* W1f = Pf;             float* as1 = Pf + 8192;
    float* ad1 = Pf + 8256;      float* b1  = Pf + 8320;
    float* W2f = Pf + 8384;      float* as2 = Pf + 12480;
    float* ad2 = Pf + 12544;     float* b2  = Pf + 12608;
    float* lw  = Pf + 12672;     float* lb  = Pf + 14720;
    float* cw  = Pf + 14752;     float* cb  = Pf + 15072;

    hipMemsetAsync(cnt, 0, sizeof(int) * (NN + 1), stream);

    probe_kernel<<<1, 64, 0, stream>>>((const unsigned int*)x, ei, flags);
    cparams_kernel<<<1, 256, 0, stream>>>(d_in[4], d_in[5], d_in[6], d_in[7],
                                          d_in[8], d_in[9], d_in[10], d_in[11],
                                          d_in[12], d_in[13], d_in[14], d_in[15],
                                          flags, Pf);
    gemm_kernel<FIN><<<NN / 16, 256, 0, stream>>>(x, W1f, H, flags, 0);
    alpha_kernel<<<NN / 4, 256, 0, stream>>>(H, as1, ad1, AS, AD);
    hist_kernel<<<(NT + 255) / 256, 256, 0, stream>>>(ei, flags, cnt);
    scanA_kernel<<<SCAN_NBLK, SCAN_B, 0, stream>>>(cnt, rowptr, bsum);
    scanB_kernel<<<1, 128, 0, stream>>>(bsum, boff, rowptr);
    scanC_kernel<<<SCAN_NBLK, SCAN_B, 0, stream>>>(rowptr, boff, cnt);
    scatter_kernel<<<(NT + 255) / 256, 256, 0, stream>>>(ei, flags, rowptr, cnt, slot);
    edge_kernel<<<NN / 4, 256, 0, stream>>>(H, AS, AD, rowptr, slot, b1, O, 1);
    gemm_kernel<HID><<<NN / 16, 256, 0, stream>>>(O, W2f, H, flags, 1);
    alpha_kernel<<<NN / 4, 256, 0, stream>>>(H, as2, ad2, AS, AD);
    edge_kernel<<<NN / 4, 256, 0, stream>>>(H, AS, AD, rowptr, slot, b2, O, 0);
    bounds_kernel<<<1, 256, 0, stream>>>(bat, flags, gstart);
    pool2_kernel<<<NG, 256, 0, stream>>>(O, gstart, pooled);
    head_kernel<<<NG, 64, 0, stream>>>(pooled, lw, lb, cw, cb, (float*)d_out);
}

// Round 6
// 506.900 us; speedup vs baseline: 2.6847x; 1.2115x over previous
//
#include <hip/hip_runtime.h>
#include <hip/hip_bf16.h>

#define NN 100000
#define NE 1600000
#define NT (NE + NN)
#define FIN 128
#define HID 64
#define NG 128
#define NC 10
#define SCAN_B 1024
#define SCAN_NBLK ((NN + SCAN_B - 1) / SCAN_B)   // 98

typedef __hip_bfloat16 bf16;

// runtime-dtype float load: f32flag ? float32 : bf16
__device__ __forceinline__ float ldx(const void* p, size_t i, int f32flag) {
    return f32flag ? ((const float*)p)[i]
                   : __bfloat162float(((const bf16*)p)[i]);
}

// ---------------- dtype probe ----------------
__global__ void probe_kernel(const unsigned int* __restrict__ xw,
                             const int* __restrict__ ei,
                             int* __restrict__ flags) {
    if (threadIdx.x != 0 || blockIdx.x != 0) return;
    int f32 = 0;
    for (int i = 0; i < 64; i++) {
        unsigned int u = xw[i];
        unsigned int lo = (u & 0xffffu) << 16;
        unsigned int hi = u & 0xffff0000u;
        float vl = __uint_as_float(lo);
        float vh = __uint_as_float(hi);
        if (!(fabsf(vl) < 1e10f)) f32 = 1;   // NaN or huge -> underlying f32
        if (!(fabsf(vh) < 1e10f)) f32 = 1;
    }
    int i64 = 1;
    for (int i = 0; i < 64; i++)
        if (ei[2 * i + 1] != 0) i64 = 0;     // high words all zero -> int64
    flags[0] = f32;
    flags[1] = i64;
}

// ---------------- param conversion into f32 block ----------------
__global__ __launch_bounds__(256) void cparams_kernel(
        const void* p0, const void* p1, const void* p2, const void* p3,
        const void* p4, const void* p5, const void* p6, const void* p7,
        const void* p8, const void* p9, const void* p10, const void* p11,
        const int* __restrict__ flags, float* __restrict__ Pf) {
    const void* ps[12] = {p0,p1,p2,p3,p4,p5,p6,p7,p8,p9,p10,p11};
    const int   sz[12] = {8192,64,64,64,4096,64,64,64,2048,32,320,10};
    const int f = flags[0];
    int off = 0;
    for (int t = 0; t < 12; t++) {
        for (int i = threadIdx.x; i < sz[t]; i += 256)
            Pf[off + i] = ldx(ps[t], i, f);
        off += sz[t];
    }
}

// ---------------- GEMM: Hb[N,HID] = X[N,K] @ W[K,HID], bf16 output ----------------
template <int K>
__global__ __launch_bounds__(256) void gemm_kernel(const void* __restrict__ X,
                                                   const float* __restrict__ Wf,
                                                   bf16* __restrict__ Hb,
                                                   const int* __restrict__ flags,
                                                   int force_f32) {
    __shared__ float Wl[K * HID];
    __shared__ float Xl[16 * K];
    const int t = threadIdx.x;
    const int f = force_f32 ? 1 : flags[0];
    for (int i = t; i < K * HID; i += 256) Wl[i] = Wf[i];
    const size_t base = (size_t)blockIdx.x * 16 * K;
    for (int i = t; i < 16 * K; i += 256) Xl[i] = ldx(X, base + i, f);
    __syncthreads();
    const int r = t >> 4;
    const int c4 = (t & 15) * 4;
    const float* xr = &Xl[r * K];
    const float* wp = &Wl[c4];
    float a0 = 0.f, a1 = 0.f, a2 = 0.f, a3 = 0.f;
#pragma unroll 4
    for (int k = 0; k < K; k++) {
        float xv = xr[k];
        float4 w4 = *(const float4*)(wp + k * HID);
        a0 += xv * w4.x; a1 += xv * w4.y; a2 += xv * w4.z; a3 += xv * w4.w;
    }
    alignas(8) bf16 tmp[4];
    tmp[0] = __float2bfloat16(a0); tmp[1] = __float2bfloat16(a1);
    tmp[2] = __float2bfloat16(a2); tmp[3] = __float2bfloat16(a3);
    *(ushort4*)&Hb[((size_t)blockIdx.x * 16 + r) * HID + c4] = *(const ushort4*)tmp;
}

// ---------------- alpha: AS[i] = Hb[i,:]·va, AD[i] = Hb[i,:]·vb ----------------
__global__ __launch_bounds__(256) void alpha_kernel(const bf16* __restrict__ Hb,
                                                    const float* __restrict__ va,
                                                    const float* __restrict__ vb,
                                                    float* __restrict__ AS,
                                                    float* __restrict__ AD) {
    int wid = (blockIdx.x * 256 + threadIdx.x) >> 6;
    int lane = threadIdx.x & 63;
    if (wid >= NN) return;
    float h = __bfloat162float(Hb[(size_t)wid * HID + lane]);
    float s1 = h * va[lane];
    float s2 = h * vb[lane];
#pragma unroll
    for (int off = 32; off; off >>= 1) {
        s1 += __shfl_xor(s1, off);
        s2 += __shfl_xor(s2, off);
    }
    if (lane == 0) { AS[wid] = s1; AD[wid] = s2; }
}

// ---------------- CSR build ----------------
__global__ __launch_bounds__(256) void hist_kernel(const int* __restrict__ ei,
                                                   const int* __restrict__ flags,
                                                   int* __restrict__ cnt) {
    int e = blockIdx.x * 256 + threadIdx.x;
    if (e >= NT) return;
    const int i64 = flags[1];
    int d;
    if (e < NE) {
        long idx = (long)NE + e;                 // dst row
        d = i64 ? ei[2 * idx] : ei[idx];
    } else d = e - NE;
    if ((unsigned)d >= NN) d = 0;
    atomicAdd(&cnt[d], 1);
}

// hierarchical exclusive scan of cnt -> rowptr (3 kernels)
__global__ __launch_bounds__(1024) void scanA_kernel(const int* __restrict__ cnt,
                                                     int* __restrict__ rowptr,
                                                     int* __restrict__ bsum) {
    const int b = blockIdx.x, t = threadIdx.x;
    const int i = b * SCAN_B + t;
    const int lane = t & 63, wv = t >> 6;
    int v = (i < NN) ? cnt[i] : 0;
    int x = v;
#pragma unroll
    for (int off = 1; off < 64; off <<= 1) {
        int y = __shfl_up(x, off);
        if (lane >= off) x += y;
    }
    __shared__ int wsum[16];
    if (lane == 63) wsum[wv] = x;
    __syncthreads();
    if (wv == 0 && lane < 16) {
        int s = wsum[lane];
#pragma unroll
        for (int off = 1; off < 16; off <<= 1) {
            int y = __shfl_up(s, off);
            if (lane >= off) s += y;
        }
        wsum[lane] = s;
    }
    __syncthreads();
    int incl = x + (wv > 0 ? wsum[wv - 1] : 0);
    if (i < NN) rowptr[i + 1] = incl;          // block-local; offset added in scanC
    if (t == SCAN_B - 1) bsum[b] = incl;
}

__global__ __launch_bounds__(128) void scanB_kernel(const int* __restrict__ bsum,
                                                    int* __restrict__ boff,
                                                    int* __restrict__ rowptr) {
    const int t = threadIdx.x;
    const int lane = t & 63, wv = t >> 6;
    int v = (t < SCAN_NBLK) ? bsum[t] : 0;
    int x = v;
#pragma unroll
    for (int off = 1; off < 64; off <<= 1) {
        int y = __shfl_up(x, off);
        if (lane >= off) x += y;
    }
    __shared__ int w0;
    if (wv == 0 && lane == 63) w0 = x;
    __syncthreads();
    int incl = x + (wv == 1 ? w0 : 0);
    if (t < SCAN_NBLK) boff[t] = incl - v;     // exclusive block offsets
    if (t == 0) rowptr[0] = 0;
}

__global__ __launch_bounds__(1024) void scanC_kernel(int* __restrict__ rowptr,
                                                     const int* __restrict__ boff,
                                                     int* __restrict__ cnt) {
    const int i = blockIdx.x * SCAN_B + threadIdx.x;
    if (i < NN) {
        rowptr[i + 1] += boff[blockIdx.x];
        cnt[i] = 0;                            // cnt reused as scatter cursor
    }
}

__global__ __launch_bounds__(256) void scatter_kernel(const int* __restrict__ ei,
                                                      const int* __restrict__ flags,
                                                      const int* __restrict__ rowptr,
                                                      int* __restrict__ cursor,
                                                      int* __restrict__ slot,
                                                      int* __restrict__ dstidx) {
    int e = blockIdx.x * 256 + threadIdx.x;
    if (e >= NT) return;
    const int i64 = flags[1];
    int s, d;
    if (e < NE) {
        s = i64 ? ei[2 * (long)e] : ei[e];
        long idx = (long)NE + e;
        d = i64 ? ei[2 * idx] : ei[idx];
    } else s = d = e - NE;
    if ((unsigned)d >= NN) d = 0;
    if ((unsigned)s >= NN) s = 0;
    int pos = atomicAdd(&cursor[d], 1);
    int j = rowptr[d] + pos;
    slot[j] = s;
    dstidx[j] = d;
}

// ---------------- per-edge attention numerator (edge-parallel, no segment max) ----------------
__global__ __launch_bounds__(256) void expe_kernel(const int* __restrict__ slot,
                                                   const int* __restrict__ dstidx,
                                                   const float* __restrict__ AS,
                                                   const float* __restrict__ AD,
                                                   float* __restrict__ EX) {
    int j = blockIdx.x * 256 + threadIdx.x;
    if (j >= NT) return;
    float e = AS[slot[j]] + AD[dstidx[j]];
    e = e > 0.f ? e : 0.2f * e;
    EX[j] = __expf(e);
}

// ---------------- fused GAT gather: one wave per destination, single pass ----------------
__global__ __launch_bounds__(256) void edge_kernel(const bf16* __restrict__ Hb,
                                                   const float* __restrict__ EX,
                                                   const int* __restrict__ rowptr,
                                                   const int* __restrict__ slot,
                                                   const float* __restrict__ bias,
                                                   float* __restrict__ OUT,
                                                   int relu_flag) {
    int wid = (blockIdx.x * 256 + threadIdx.x) >> 6;
    int lane = threadIdx.x & 63;
    if (wid >= NN) return;
    const int beg = rowptr[wid], end = rowptr[wid + 1];
    float acc0 = 0.f, acc1 = 0.f, acc2 = 0.f, acc3 = 0.f, dsum = 0.f;
    for (int cbeg = beg; cbeg < end; cbeg += 64) {
        int j = cbeg + lane;
        float ex = 0.f; int s = 0;
        if (j < end) { s = slot[j]; ex = EX[j]; dsum += ex; }
        int cn = min(64, end - cbeg);
        int u = 0;
        for (; u + 4 <= cn; u += 4) {
            int s0 = __shfl(s, u),     s1 = __shfl(s, u + 1);
            int s2 = __shfl(s, u + 2), s3 = __shfl(s, u + 3);
            float e0 = __shfl(ex, u),     e1 = __shfl(ex, u + 1);
            float e2 = __shfl(ex, u + 2), e3 = __shfl(ex, u + 3);
            float h0 = __bfloat162float(Hb[(size_t)s0 * HID + lane]);
            float h1 = __bfloat162float(Hb[(size_t)s1 * HID + lane]);
            float h2 = __bfloat162float(Hb[(size_t)s2 * HID + lane]);
            float h3 = __bfloat162float(Hb[(size_t)s3 * HID + lane]);
            acc0 += e0 * h0; acc1 += e1 * h1; acc2 += e2 * h2; acc3 += e3 * h3;
        }
        for (; u < cn; ++u) {
            int su = __shfl(s, u);
            float eu = __shfl(ex, u);
            acc0 += eu * __bfloat162float(Hb[(size_t)su * HID + lane]);
        }
    }
#pragma unroll
    for (int off = 32; off; off >>= 1) dsum += __shfl_xor(dsum, off);
    float o = (acc0 + acc1 + acc2 + acc3) / dsum + bias[lane];
    if (relu_flag) o = fmaxf(o, 0.f);
    OUT[(size_t)wid * HID + lane] = o;
}

// ---------------- pooling: graph bounds + per-graph block mean ----------------
__global__ __launch_bounds__(256) void bounds_kernel(const int* __restrict__ bat,
                                                     const int* __restrict__ flags,
                                                     int* __restrict__ gstart) {
    int g = threadIdx.x;
    if (g > NG) return;
    const int i64 = flags[1];
    int lo = 0, hi = NN;
    while (lo < hi) {                       // first i with bat[i] >= g
        int mid = (lo + hi) >> 1;
        int v = i64 ? bat[2 * (long)mid] : bat[mid];
        if (v < g) lo = mid + 1; else hi = mid;
    }
    gstart[g] = lo;
}

__global__ __launch_bounds__(256) void pool2_kernel(const float* __restrict__ O,
                                                    const int* __restrict__ gstart,
                                                    float* __restrict__ pooled) {
    const int g = blockIdx.x;
    const int lane = threadIdx.x & 63;
    const int wv = threadIdx.x >> 6;
    const int beg = gstart[g], end = gstart[g + 1];
    float acc = 0.f;
    for (int i = beg + wv; i < end; i += 4)
        acc += O[(size_t)i * HID + lane];
    __shared__ float red[4][64];
    red[wv][lane] = acc;
    __syncthreads();
    if (wv == 0) {
        float s = red[0][lane] + red[1][lane] + red[2][lane] + red[3][lane];
        float cntg = (float)(end - beg);
        pooled[g * HID + lane] = s / fmaxf(cntg, 1.f);   // fused mean
    }
}

// ---------------- head: one block per graph, LDS staging ----------------
__global__ __launch_bounds__(64) void head_kernel(const float* __restrict__ pooled,
                                                  const float* __restrict__ lw, const float* __restrict__ lb,
                                                  const float* __restrict__ cw, const float* __restrict__ cb,
                                                  float* __restrict__ out) {
    const int g = blockIdx.x;
    const int t = threadIdx.x;
    __shared__ float p[HID];
    __shared__ float z[32];
    __shared__ float lg[NC];
    p[t] = pooled[g * HID + t];
    __syncthreads();
    if (t < 32) {
        float acc = lb[t];
#pragma unroll
        for (int k = 0; k < HID; k++) acc += p[k] * lw[k * 32 + t];
        z[t] = fmaxf(acc, 0.f);
    }
    __syncthreads();
    if (t < NC) {
        float acc = cb[t];
#pragma unroll
        for (int j = 0; j < 32; j++) acc += z[j] * cw[j * NC + t];
        lg[t] = acc;
    }
    __syncthreads();
    if (t < NC) {
        float mx = -1e30f;
#pragma unroll
        for (int c = 0; c < NC; c++) mx = fmaxf(mx, lg[c]);
        float s = 0.f;
#pragma unroll
        for (int c = 0; c < NC; c++) s += __expf(lg[c] - mx);
        out[g * NC + t] = lg[t] - mx - __logf(s);
    }
}

extern "C" void kernel_launch(void* const* d_in, const int* in_sizes, int n_in,
                              void* d_out, int out_size, void* d_ws, size_t ws_size,
                              hipStream_t stream) {
    const void* x   = d_in[0];
    const int*  ei  = (const int*)d_in[1];
    // d_in[2] edge_weight: unused (GATConv has no lin_edge)
    const int*  bat = (const int*)d_in[3];

    char* w = (char*)d_ws;
    bf16* Hb      = (bf16*)w;  w += sizeof(bf16) * NN * HID;
    float* O      = (float*)w; w += sizeof(float) * NN * HID;
    float* AS     = (float*)w; w += sizeof(float) * NN;
    float* AD     = (float*)w; w += sizeof(float) * NN;
    int* cnt      = (int*)w;   w += sizeof(int) * (NN + 1);   // reused as cursor
    int* rowptr   = (int*)w;   w += sizeof(int) * (NN + 1);
    int* slot     = (int*)w;   w += sizeof(int) * NT;
    int* dstidx   = (int*)w;   w += sizeof(int) * NT;
    float* EX     = (float*)w; w += sizeof(float) * NT;
    float* pooled = (float*)w; w += sizeof(float) * NG * HID;
    int* gstart   = (int*)w;   w += sizeof(int) * (NG + 1);
    int* bsum     = (int*)w;   w += sizeof(int) * SCAN_NBLK;
    int* boff     = (int*)w;   w += sizeof(int) * SCAN_NBLK;
    int* flags    = (int*)w;   w += sizeof(int) * 2;
    float* Pf     = (float*)w; w += sizeof(float) * 16384;

    // Pf offsets
    float* W1f = Pf;             float* as1 = Pf + 8192;
    float* ad1 = Pf + 8256;      float* b1  = Pf + 8320;
    float* W2f = Pf + 8384;      float* as2 = Pf + 12480;
    float* ad2 = Pf + 12544;     float* b2  = Pf + 12608;
    float* lw  = Pf + 12672;     float* lb  = Pf + 14720;
    float* cw  = Pf + 14752;     float* cb  = Pf + 15072;

    hipMemsetAsync(cnt, 0, sizeof(int) * (NN + 1), stream);

    probe_kernel<<<1, 64, 0, stream>>>((const unsigned int*)x, ei, flags);
    cparams_kernel<<<1, 256, 0, stream>>>(d_in[4], d_in[5], d_in[6], d_in[7],
                                          d_in[8], d_in[9], d_in[10], d_in[11],
                                          d_in[12], d_in[13], d_in[14], d_in[15],
                                          flags, Pf);
    // CSR build (independent of features)
    hist_kernel<<<(NT + 255) / 256, 256, 0, stream>>>(ei, flags, cnt);
    scanA_kernel<<<SCAN_NBLK, SCAN_B, 0, stream>>>(cnt, rowptr, bsum);
    scanB_kernel<<<1, 128, 0, stream>>>(bsum, boff, rowptr);
    scanC_kernel<<<SCAN_NBLK, SCAN_B, 0, stream>>>(rowptr, boff, cnt);
    scatter_kernel<<<(NT + 255) / 256, 256, 0, stream>>>(ei, flags, rowptr, cnt, slot, dstidx);
    // layer 1
    gemm_kernel<FIN><<<NN / 16, 256, 0, stream>>>(x, W1f, Hb, flags, 0);
    alpha_kernel<<<NN / 4, 256, 0, stream>>>(Hb, as1, ad1, AS, AD);
    expe_kernel<<<(NT + 255) / 256, 256, 0, stream>>>(slot, dstidx, AS, AD, EX);
    edge_kernel<<<NN / 4, 256, 0, stream>>>(Hb, EX, rowptr, slot, b1, O, 1);
    // layer 2
    gemm_kernel<HID><<<NN / 16, 256, 0, stream>>>(O, W2f, Hb, flags, 1);
    alpha_kernel<<<NN / 4, 256, 0, stream>>>(Hb, as2, ad2, AS, AD);
    expe_kernel<<<(NT + 255) / 256, 256, 0, stream>>>(slot, dstidx, AS, AD, EX);
    edge_kernel<<<NN / 4, 256, 0, stream>>>(Hb, EX, rowptr, slot, b2, O, 0);
    // readout
    bounds_kernel<<<1, 256, 0, stream>>>(bat, flags, gstart);
    pool2_kernel<<<NG, 256, 0, stream>>>(O, gstart, pooled);
    head_kernel<<<NG, 64, 0, stream>>>(pooled, lw, lb, cw, cb, (float*)d_out);
}

// Round 7
// 481.071 us; speedup vs baseline: 2.8288x; 1.0537x over previous
//
#include <hip/hip_runtime.h>
#include <hip/hip_bf16.h>

#define NN 100000
#define NE 1600000
#define NT (NE + NN)
#define FIN 128
#define HID 64
#define NG 128
#define NC 10
#define SCAN_B 1024
#define SCAN_NBLK ((NN + SCAN_B - 1) / SCAN_B)   // 98

typedef __hip_bfloat16 bf16;

// runtime-dtype float load: f32flag ? float32 : bf16
__device__ __forceinline__ float ldx(const void* p, size_t i, int f32flag) {
    return f32flag ? ((const float*)p)[i]
                   : __bfloat162float(((const bf16*)p)[i]);
}

// ---------------- dtype probe ----------------
__global__ void probe_kernel(const unsigned int* __restrict__ xw,
                             const int* __restrict__ ei,
                             int* __restrict__ flags) {
    if (threadIdx.x != 0 || blockIdx.x != 0) return;
    int f32 = 0;
    for (int i = 0; i < 64; i++) {
        unsigned int u = xw[i];
        unsigned int lo = (u & 0xffffu) << 16;
        unsigned int hi = u & 0xffff0000u;
        float vl = __uint_as_float(lo);
        float vh = __uint_as_float(hi);
        if (!(fabsf(vl) < 1e10f)) f32 = 1;   // NaN or huge -> underlying f32
        if (!(fabsf(vh) < 1e10f)) f32 = 1;
    }
    int i64 = 1;
    for (int i = 0; i < 64; i++)
        if (ei[2 * i + 1] != 0) i64 = 0;     // high words all zero -> int64
    flags[0] = f32;
    flags[1] = i64;
}

// ---------------- param conversion into f32 block ----------------
__global__ __launch_bounds__(256) void cparams_kernel(
        const void* p0, const void* p1, const void* p2, const void* p3,
        const void* p4, const void* p5, const void* p6, const void* p7,
        const void* p8, const void* p9, const void* p10, const void* p11,
        const int* __restrict__ flags, float* __restrict__ Pf) {
    const void* ps[12] = {p0,p1,p2,p3,p4,p5,p6,p7,p8,p9,p10,p11};
    const int   sz[12] = {8192,64,64,64,4096,64,64,64,2048,32,320,10};
    const int f = flags[0];
    int off = 0;
    for (int t = 0; t < 12; t++) {
        for (int i = threadIdx.x; i < sz[t]; i += 256)
            Pf[off + i] = ldx(ps[t], i, f);
        off += sz[t];
    }
}

// ---------------- GEMM: Hb[N,HID] = X[N,K] @ W[K,HID], bf16 output ----------------
template <int K>
__global__ __launch_bounds__(256) void gemm_kernel(const void* __restrict__ X,
                                                   const float* __restrict__ Wf,
                                                   bf16* __restrict__ Hb,
                                                   const int* __restrict__ flags,
                                                   int force_f32) {
    __shared__ float Wl[K * HID];
    __shared__ float Xl[16 * K];
    const int t = threadIdx.x;
    const int f = force_f32 ? 1 : flags[0];
    for (int i = t; i < K * HID; i += 256) Wl[i] = Wf[i];
    const size_t base = (size_t)blockIdx.x * 16 * K;
    for (int i = t; i < 16 * K; i += 256) Xl[i] = ldx(X, base + i, f);
    __syncthreads();
    const int r = t >> 4;
    const int c4 = (t & 15) * 4;
    const float* xr = &Xl[r * K];
    const float* wp = &Wl[c4];
    float a0 = 0.f, a1 = 0.f, a2 = 0.f, a3 = 0.f;
#pragma unroll 4
    for (int k = 0; k < K; k++) {
        float xv = xr[k];
        float4 w4 = *(const float4*)(wp + k * HID);
        a0 += xv * w4.x; a1 += xv * w4.y; a2 += xv * w4.z; a3 += xv * w4.w;
    }
    alignas(8) bf16 tmp[4];
    tmp[0] = __float2bfloat16(a0); tmp[1] = __float2bfloat16(a1);
    tmp[2] = __float2bfloat16(a2); tmp[3] = __float2bfloat16(a3);
    *(ushort4*)&Hb[((size_t)blockIdx.x * 16 + r) * HID + c4] = *(const ushort4*)tmp;
}

// ---------------- alpha: AS[i] = Hb[i,:]·va, AD[i] = Hb[i,:]·vb ----------------
__global__ __launch_bounds__(256) void alpha_kernel(const bf16* __restrict__ Hb,
                                                    const float* __restrict__ va,
                                                    const float* __restrict__ vb,
                                                    float* __restrict__ AS,
                                                    float* __restrict__ AD) {
    int wid = (blockIdx.x * 256 + threadIdx.x) >> 6;
    int lane = threadIdx.x & 63;
    if (wid >= NN) return;
    float h = __bfloat162float(Hb[(size_t)wid * HID + lane]);
    float s1 = h * va[lane];
    float s2 = h * vb[lane];
#pragma unroll
    for (int off = 32; off; off >>= 1) {
        s1 += __shfl_xor(s1, off);
        s2 += __shfl_xor(s2, off);
    }
    if (lane == 0) { AS[wid] = s1; AD[wid] = s2; }
}

// ---------------- CSR build ----------------
__global__ __launch_bounds__(256) void hist_kernel(const int* __restrict__ ei,
                                                   const int* __restrict__ flags,
                                                   int* __restrict__ cnt) {
    int e = blockIdx.x * 256 + threadIdx.x;
    if (e >= NT) return;
    const int i64 = flags[1];
    int d;
    if (e < NE) {
        long idx = (long)NE + e;                 // dst row
        d = i64 ? ei[2 * idx] : ei[idx];
    } else d = e - NE;
    if ((unsigned)d >= NN) d = 0;
    atomicAdd(&cnt[d], 1);
}

// hierarchical exclusive scan of cnt -> rowptr (3 kernels)
__global__ __launch_bounds__(1024) void scanA_kernel(const int* __restrict__ cnt,
                                                     int* __restrict__ rowptr,
                                                     int* __restrict__ bsum) {
    const int b = blockIdx.x, t = threadIdx.x;
    const int i = b * SCAN_B + t;
    const int lane = t & 63, wv = t >> 6;
    int v = (i < NN) ? cnt[i] : 0;
    int x = v;
#pragma unroll
    for (int off = 1; off < 64; off <<= 1) {
        int y = __shfl_up(x, off);
        if (lane >= off) x += y;
    }
    __shared__ int wsum[16];
    if (lane == 63) wsum[wv] = x;
    __syncthreads();
    if (wv == 0 && lane < 16) {
        int s = wsum[lane];
#pragma unroll
        for (int off = 1; off < 16; off <<= 1) {
            int y = __shfl_up(s, off);
            if (lane >= off) s += y;
        }
        wsum[lane] = s;
    }
    __syncthreads();
    int incl = x + (wv > 0 ? wsum[wv - 1] : 0);
    if (i < NN) rowptr[i + 1] = incl;          // block-local; offset added in scanC
    if (t == SCAN_B - 1) bsum[b] = incl;
}

__global__ __launch_bounds__(128) void scanB_kernel(const int* __restrict__ bsum,
                                                    int* __restrict__ boff,
                                                    int* __restrict__ rowptr) {
    const int t = threadIdx.x;
    const int lane = t & 63, wv = t >> 6;
    int v = (t < SCAN_NBLK) ? bsum[t] : 0;
    int x = v;
#pragma unroll
    for (int off = 1; off < 64; off <<= 1) {
        int y = __shfl_up(x, off);
        if (lane >= off) x += y;
    }
    __shared__ int w0;
    if (wv == 0 && lane == 63) w0 = x;
    __syncthreads();
    int incl = x + (wv == 1 ? w0 : 0);
    if (t < SCAN_NBLK) boff[t] = incl - v;     // exclusive block offsets
    if (t == 0) rowptr[0] = 0;
}

__global__ __launch_bounds__(1024) void scanC_kernel(int* __restrict__ rowptr,
                                                     const int* __restrict__ boff,
                                                     int* __restrict__ cnt) {
    const int i = blockIdx.x * SCAN_B + threadIdx.x;
    if (i < NN) {
        rowptr[i + 1] += boff[blockIdx.x];
        cnt[i] = 0;                            // cnt reused as scatter cursor
    }
}

__global__ __launch_bounds__(256) void scatter_kernel(const int* __restrict__ ei,
                                                      const int* __restrict__ flags,
                                                      const int* __restrict__ rowptr,
                                                      int* __restrict__ cursor,
                                                      int* __restrict__ slot) {
    int e = blockIdx.x * 256 + threadIdx.x;
    if (e >= NT) return;
    const int i64 = flags[1];
    int s, d;
    if (e < NE) {
        s = i64 ? ei[2 * (long)e] : ei[e];
        long idx = (long)NE + e;
        d = i64 ? ei[2 * idx] : ei[idx];
    } else s = d = e - NE;
    if ((unsigned)d >= NN) d = 0;
    if ((unsigned)s >= NN) s = 0;
    int pos = atomicAdd(&cursor[d], 1);
    slot[rowptr[d] + pos] = s;
}

// ---------------- fused GAT gather: one wave per destination, single pass ----------------
__global__ __launch_bounds__(256) void edge_kernel(const bf16* __restrict__ Hb,
                                                   const float* __restrict__ AS,
                                                   const float* __restrict__ AD,
                                                   const int* __restrict__ rowptr,
                                                   const int* __restrict__ slot,
                                                   const float* __restrict__ bias,
                                                   float* __restrict__ OUT,
                                                   int relu_flag) {
    int wid = (blockIdx.x * 256 + threadIdx.x) >> 6;
    int lane = threadIdx.x & 63;
    if (wid >= NN) return;
    const int beg = rowptr[wid], end = rowptr[wid + 1];
    const float ad = AD[wid];
    float acc0 = 0.f, acc1 = 0.f, acc2 = 0.f, acc3 = 0.f, dsum = 0.f;
    for (int cbeg = beg; cbeg < end; cbeg += 64) {
        int j = cbeg + lane;
        float ex = 0.f; int s = 0;
        if (j < end) {
            s = slot[j];
            float e = AS[s] + ad;                 // AS gather: 400 KB, L2-resident
            e = e > 0.f ? e : 0.2f * e;
            ex = __expf(e);
            dsum += ex;
        }
        int cn = min(64, end - cbeg);
        int u = 0;
        for (; u + 4 <= cn; u += 4) {
            int s0 = __shfl(s, u),     s1 = __shfl(s, u + 1);
            int s2 = __shfl(s, u + 2), s3 = __shfl(s, u + 3);
            float e0 = __shfl(ex, u),     e1 = __shfl(ex, u + 1);
            float e2 = __shfl(ex, u + 2), e3 = __shfl(ex, u + 3);
            float h0 = __bfloat162float(Hb[(size_t)s0 * HID + lane]);
            float h1 = __bfloat162float(Hb[(size_t)s1 * HID + lane]);
            float h2 = __bfloat162float(Hb[(size_t)s2 * HID + lane]);
            float h3 = __bfloat162float(Hb[(size_t)s3 * HID + lane]);
            acc0 += e0 * h0; acc1 += e1 * h1; acc2 += e2 * h2; acc3 += e3 * h3;
        }
        for (; u < cn; ++u) {
            int su = __shfl(s, u);
            float eu = __shfl(ex, u);
            acc0 += eu * __bfloat162float(Hb[(size_t)su * HID + lane]);
        }
    }
#pragma unroll
    for (int off = 32; off; off >>= 1) dsum += __shfl_xor(dsum, off);
    float o = (acc0 + acc1 + acc2 + acc3) / dsum + bias[lane];
    if (relu_flag) o = fmaxf(o, 0.f);
    OUT[(size_t)wid * HID + lane] = o;
}

// ---------------- pooling: graph bounds + per-graph block mean ----------------
__global__ __launch_bounds__(256) void bounds_kernel(const int* __restrict__ bat,
                                                     const int* __restrict__ flags,
                                                     int* __restrict__ gstart) {
    int g = threadIdx.x;
    if (g > NG) return;
    const int i64 = flags[1];
    int lo = 0, hi = NN;
    while (lo < hi) {                       // first i with bat[i] >= g
        int mid = (lo + hi) >> 1;
        int v = i64 ? bat[2 * (long)mid] : bat[mid];
        if (v < g) lo = mid + 1; else hi = mid;
    }
    gstart[g] = lo;
}

__global__ __launch_bounds__(256) void pool2_kernel(const float* __restrict__ O,
                                                    const int* __restrict__ gstart,
                                                    float* __restrict__ pooled) {
    const int g = blockIdx.x;
    const int lane = threadIdx.x & 63;
    const int wv = threadIdx.x >> 6;
    const int beg = gstart[g], end = gstart[g + 1];
    float acc = 0.f;
    for (int i = beg + wv; i < end; i += 4)
        acc += O[(size_t)i * HID + lane];
    __shared__ float red[4][64];
    red[wv][lane] = acc;
    __syncthreads();
    if (wv == 0) {
        float s = red[0][lane] + red[1][lane] + red[2][lane] + red[3][lane];
        float cntg = (float)(end - beg);
        pooled[g * HID + lane] = s / fmaxf(cntg, 1.f);   // fused mean
    }
}

// ---------------- head: one block per graph, LDS staging ----------------
__global__ __launch_bounds__(64) void head_kernel(const float* __restrict__ pooled,
                                                  const float* __restrict__ lw, const float* __restrict__ lb,
                                                  const float* __restrict__ cw, const float* __restrict__ cb,
                                                  float* __restrict__ out) {
    const int g = blockIdx.x;
    const int t = threadIdx.x;
    __shared__ float p[HID];
    __shared__ float z[32];
    __shared__ float lg[NC];
    p[t] = pooled[g * HID + t];
    __syncthreads();
    if (t < 32) {
        float acc = lb[t];
#pragma unroll
        for (int k = 0; k < HID; k++) acc += p[k] * lw[k * 32 + t];
        z[t] = fmaxf(acc, 0.f);
    }
    __syncthreads();
    if (t < NC) {
        float acc = cb[t];
#pragma unroll
        for (int j = 0; j < 32; j++) acc += z[j] * cw[j * NC + t];
        lg[t] = acc;
    }
    __syncthreads();
    if (t < NC) {
        float mx = -1e30f;
#pragma unroll
        for (int c = 0; c < NC; c++) mx = fmaxf(mx, lg[c]);
        float s = 0.f;
#pragma unroll
        for (int c = 0; c < NC; c++) s += __expf(lg[c] - mx);
        out[g * NC + t] = lg[t] - mx - __logf(s);
    }
}

extern "C" void kernel_launch(void* const* d_in, const int* in_sizes, int n_in,
                              void* d_out, int out_size, void* d_ws, size_t ws_size,
                              hipStream_t stream) {
    const void* x   = d_in[0];
    const int*  ei  = (const int*)d_in[1];
    // d_in[2] edge_weight: unused (GATConv has no lin_edge)
    const int*  bat = (const int*)d_in[3];

    char* w = (char*)d_ws;
    bf16* Hb      = (bf16*)w;  w += sizeof(bf16) * NN * HID;
    float* O      = (float*)w; w += sizeof(float) * NN * HID;
    float* AS     = (float*)w; w += sizeof(float) * NN;
    float* AD     = (float*)w; w += sizeof(float) * NN;
    int* cnt      = (int*)w;   w += sizeof(int) * (NN + 1);   // reused as cursor
    int* rowptr   = (int*)w;   w += sizeof(int) * (NN + 1);
    int* slot     = (int*)w;   w += sizeof(int) * NT;
    float* pooled = (float*)w; w += sizeof(float) * NG * HID;
    int* gstart   = (int*)w;   w += sizeof(int) * (NG + 1);
    int* bsum     = (int*)w;   w += sizeof(int) * SCAN_NBLK;
    int* boff     = (int*)w;   w += sizeof(int) * SCAN_NBLK;
    int* flags    = (int*)w;   w += sizeof(int) * 2;
    float* Pf     = (float*)w; w += sizeof(float) * 16384;

    // Pf offsets
    float* W1f = Pf;             float* as1 = Pf + 8192;
    float* ad1 = Pf + 8256;      float* b1  = Pf + 8320;
    float* W2f = Pf + 8384;      float* as2 = Pf + 12480;
    float* ad2 = Pf + 12544;     float* b2  = Pf + 12608;
    float* lw  = Pf + 12672;     float* lb  = Pf + 14720;
    float* cw  = Pf + 14752;     float* cb  = Pf + 15072;

    hipMemsetAsync(cnt, 0, sizeof(int) * (NN + 1), stream);

    probe_kernel<<<1, 64, 0, stream>>>((const unsigned int*)x, ei, flags);
    cparams_kernel<<<1, 256, 0, stream>>>(d_in[4], d_in[5], d_in[6], d_in[7],
                                          d_in[8], d_in[9], d_in[10], d_in[11],
                                          d_in[12], d_in[13], d_in[14], d_in[15],
                                          flags, Pf);
    // CSR build (independent of features)
    hist_kernel<<<(NT + 255) / 256, 256, 0, stream>>>(ei, flags, cnt);
    scanA_kernel<<<SCAN_NBLK, SCAN_B, 0, stream>>>(cnt, rowptr, bsum);
    scanB_kernel<<<1, 128, 0, stream>>>(bsum, boff, rowptr);
    scanC_kernel<<<SCAN_NBLK, SCAN_B, 0, stream>>>(rowptr, boff, cnt);
    scatter_kernel<<<(NT + 255) / 256, 256, 0, stream>>>(ei, flags, rowptr, cnt, slot);
    // layer 1
    gemm_kernel<FIN><<<NN / 16, 256, 0, stream>>>(x, W1f, Hb, flags, 0);
    alpha_kernel<<<NN / 4, 256, 0, stream>>>(Hb, as1, ad1, AS, AD);
    edge_kernel<<<NN / 4, 256, 0, stream>>>(Hb, AS, AD, rowptr, slot, b1, O, 1);
    // layer 2
    gemm_kernel<HID><<<NN / 16, 256, 0, stream>>>(O, W2f, Hb, flags, 1);
    alpha_kernel<<<NN / 4, 256, 0, stream>>>(Hb, as2, ad2, AS, AD);
    edge_kernel<<<NN / 4, 256, 0, stream>>>(Hb, AS, AD, rowptr, slot, b2, O, 0);
    // readout
    bounds_kernel<<<1, 256, 0, stream>>>(bat, flags, gstart);
    pool2_kernel<<<NG, 256, 0, stream>>>(O, gstart, pooled);
    head_kernel<<<NG, 64, 0, stream>>>(pooled, lw, lb, cw, cb, (float*)d_out);
}

// Round 8
// 379.734 us; speedup vs baseline: 3.5837x; 1.2669x over previous
//
#include <hip/hip_runtime.h>
#include <hip/hip_bf16.h>

#define NN 100000
#define NE 1600000
#define NT (NE + NN)
#define FIN 128
#define HID 64
#define NG 128
#define NC 10
#define BSHIFT 8
#define NBUCK ((NN + 255) >> 8)          // 391 buckets of 256 nodes
#define A2_EPB 4096                       // edges per block in bucket-scatter

typedef __hip_bfloat16 bf16;

// runtime-dtype float load: f32flag ? float32 : bf16
__device__ __forceinline__ float ldx(const void* p, size_t i, int f32flag) {
    return f32flag ? ((const float*)p)[i]
                   : __bfloat162float(((const bf16*)p)[i]);
}

// ---------------- dtype probe ----------------
__global__ void probe_kernel(const unsigned int* __restrict__ xw,
                             const int* __restrict__ ei,
                             int* __restrict__ flags) {
    if (threadIdx.x != 0 || blockIdx.x != 0) return;
    int f32 = 0;
    for (int i = 0; i < 64; i++) {
        unsigned int u = xw[i];
        unsigned int lo = (u & 0xffffu) << 16;
        unsigned int hi = u & 0xffff0000u;
        float vl = __uint_as_float(lo);
        float vh = __uint_as_float(hi);
        if (!(fabsf(vl) < 1e10f)) f32 = 1;   // NaN or huge -> underlying f32
        if (!(fabsf(vh) < 1e10f)) f32 = 1;
    }
    int i64 = 1;
    for (int i = 0; i < 64; i++)
        if (ei[2 * i + 1] != 0) i64 = 0;     // high words all zero -> int64
    flags[0] = f32;
    flags[1] = i64;
}

// ---------------- param conversion into f32 block ----------------
__global__ __launch_bounds__(256) void cparams_kernel(
        const void* p0, const void* p1, const void* p2, const void* p3,
        const void* p4, const void* p5, const void* p6, const void* p7,
        const void* p8, const void* p9, const void* p10, const void* p11,
        const int* __restrict__ flags, float* __restrict__ Pf) {
    const void* ps[12] = {p0,p1,p2,p3,p4,p5,p6,p7,p8,p9,p10,p11};
    const int   sz[12] = {8192,64,64,64,4096,64,64,64,2048,32,320,10};
    const int f = flags[0];
    int off = 0;
    for (int t = 0; t < 12; t++) {
        for (int i = threadIdx.x; i < sz[t]; i += 256)
            Pf[off + i] = ldx(ps[t], i, f);
        off += sz[t];
    }
}

// ---------------- GEMM: Hb[N,HID] = X[N,K] @ W[K,HID], bf16 output ----------------
template <int K>
__global__ __launch_bounds__(256) void gemm_kernel(const void* __restrict__ X,
                                                   const float* __restrict__ Wf,
                                                   bf16* __restrict__ Hb,
                                                   const int* __restrict__ flags,
                                                   int force_f32) {
    __shared__ float Wl[K * HID];
    __shared__ float Xl[16 * K];
    const int t = threadIdx.x;
    const int f = force_f32 ? 1 : flags[0];
    for (int i = t; i < K * HID; i += 256) Wl[i] = Wf[i];
    const size_t base = (size_t)blockIdx.x * 16 * K;
    for (int i = t; i < 16 * K; i += 256) Xl[i] = ldx(X, base + i, f);
    __syncthreads();
    const int r = t >> 4;
    const int c4 = (t & 15) * 4;
    const float* xr = &Xl[r * K];
    const float* wp = &Wl[c4];
    float a0 = 0.f, a1 = 0.f, a2 = 0.f, a3 = 0.f;
#pragma unroll 4
    for (int k = 0; k < K; k++) {
        float xv = xr[k];
        float4 w4 = *(const float4*)(wp + k * HID);
        a0 += xv * w4.x; a1 += xv * w4.y; a2 += xv * w4.z; a3 += xv * w4.w;
    }
    alignas(8) bf16 tmp[4];
    tmp[0] = __float2bfloat16(a0); tmp[1] = __float2bfloat16(a1);
    tmp[2] = __float2bfloat16(a2); tmp[3] = __float2bfloat16(a3);
    *(ushort4*)&Hb[((size_t)blockIdx.x * 16 + r) * HID + c4] = *(const ushort4*)tmp;
}

// ---------------- alpha: AS[i] = Hb[i,:]·va, AD[i] = Hb[i,:]·vb ----------------
__global__ __launch_bounds__(256) void alpha_kernel(const bf16* __restrict__ Hb,
                                                    const float* __restrict__ va,
                                                    const float* __restrict__ vb,
                                                    float* __restrict__ AS,
                                                    float* __restrict__ AD) {
    int wid = (blockIdx.x * 256 + threadIdx.x) >> 6;
    int lane = threadIdx.x & 63;
    if (wid >= NN) return;
    float h = __bfloat162float(Hb[(size_t)wid * HID + lane]);
    float s1 = h * va[lane];
    float s2 = h * vb[lane];
#pragma unroll
    for (int off = 32; off; off >>= 1) {
        s1 += __shfl_xor(s1, off);
        s2 += __shfl_xor(s2, off);
    }
    if (lane == 0) { AS[wid] = s1; AD[wid] = s2; }
}

// ---------------- bucket CSR build ----------------
// A1: bucket histogram (LDS-aggregated)
__global__ __launch_bounds__(256) void bhistA_kernel(const int* __restrict__ ei,
                                                     const int* __restrict__ flags,
                                                     int* __restrict__ gcnt) {
    __shared__ int lc[NBUCK];
    for (int i = threadIdx.x; i < NBUCK; i += 256) lc[i] = 0;
    __syncthreads();
    const int i64 = flags[1];
    const int base = blockIdx.x * 8192;
    for (int i = threadIdx.x; i < 8192; i += 256) {
        int e = base + i;
        if (e >= NT) break;
        int d;
        if (e < NE) { long idx = (long)NE + e; d = i64 ? ei[2 * idx] : ei[idx]; }
        else d = e - NE;
        if ((unsigned)d >= NN) d = 0;
        atomicAdd(&lc[d >> BSHIFT], 1);
    }
    __syncthreads();
    for (int i = threadIdx.x; i < NBUCK; i += 256)
        if (lc[i]) atomicAdd(&gcnt[i], lc[i]);
}

// bucket scan: one wave, sequential 64-wide shfl segments
__global__ __launch_bounds__(64) void bscan_kernel(const int* __restrict__ gcnt,
                                                   int* __restrict__ gbase,
                                                   int* __restrict__ gcursor) {
    const int lane = threadIdx.x;
    int carry = 0;
    for (int base = 0; base < NBUCK; base += 64) {
        int idx = base + lane;
        int v = (idx < NBUCK) ? gcnt[idx] : 0;
        int x = v;
#pragma unroll
        for (int off = 1; off < 64; off <<= 1) {
            int y = __shfl_up(x, off);
            if (lane >= off) x += y;
        }
        int excl = carry + x - v;
        if (idx < NBUCK) { gbase[idx] = excl; gcursor[idx] = excl; }
        carry += __shfl(x, 63);
    }
    if (lane == 0) gbase[NBUCK] = carry;     // == NT
}

// A2: bucket scatter — per-block dense runs per bucket (full-line writes)
__global__ __launch_bounds__(256) void bscat_kernel(const int* __restrict__ ei,
                                                    const int* __restrict__ flags,
                                                    int* __restrict__ gcursor,
                                                    int2* __restrict__ bucketA) {
    __shared__ int lc[NBUCK];
    __shared__ int lpos[NBUCK];
    __shared__ int lcur[NBUCK];
    for (int i = threadIdx.x; i < NBUCK; i += 256) { lc[i] = 0; lcur[i] = 0; }
    __syncthreads();
    const int i64 = flags[1];
    const int base = blockIdx.x * A2_EPB;
    int sarr[16], darr[16];
#pragma unroll
    for (int i = 0; i < 16; i++) {
        int e = base + i * 256 + threadIdx.x;
        int s = -1, d = 0;
        if (e < NT) {
            if (e < NE) {
                s = i64 ? ei[2 * (long)e] : ei[e];
                long idx = (long)NE + e;
                d = i64 ? ei[2 * idx] : ei[idx];
            } else s = d = e - NE;
            if ((unsigned)d >= NN) d = 0;
            if ((unsigned)s >= NN) s = 0;
            atomicAdd(&lc[d >> BSHIFT], 1);
        }
        sarr[i] = s; darr[i] = d;
    }
    __syncthreads();
    for (int i = threadIdx.x; i < NBUCK; i += 256)
        lpos[i] = lc[i] ? atomicAdd(&gcursor[i], lc[i]) : 0;
    __syncthreads();
#pragma unroll
    for (int i = 0; i < 16; i++) {
        if (sarr[i] >= 0) {
            int b = darr[i] >> BSHIFT;
            int off = atomicAdd(&lcur[b], 1);
            bucketA[lpos[b] + off] = make_int2(sarr[i], darr[i]);
        }
    }
}

// pass B: per-bucket exact CSR (LDS counters + scan, no global atomics)
__global__ __launch_bounds__(256) void csr_kernel(const int2* __restrict__ bucketA,
                                                  const int* __restrict__ gbase,
                                                  int* __restrict__ rowptr,
                                                  int* __restrict__ slot) {
    const int b = blockIdx.x;
    const int nbase = b << BSHIFT;
    const int nb = min(256, NN - nbase);
    const int ebeg = gbase[b], eend = gbase[b + 1];
    __shared__ int cnt[256];
    __shared__ int excl[257];
    __shared__ int cur[256];
    const int t = threadIdx.x;
    cnt[t] = 0; cur[t] = 0;
    __syncthreads();
    for (int i = ebeg + t; i < eend; i += 256)
        atomicAdd(&cnt[bucketA[i].y - nbase], 1);
    __syncthreads();
    if (t < 64) {                              // wave 0 scans 256 entries
        int carry = 0;
        for (int s0 = 0; s0 < 256; s0 += 64) {
            int v = cnt[s0 + t];
            int x = v;
#pragma unroll
            for (int off = 1; off < 64; off <<= 1) {
                int y = __shfl_up(x, off);
                if (t >= off) x += y;
            }
            excl[s0 + t] = carry + x - v;
            carry += __shfl(x, 63);
        }
        if (t == 0) excl[256] = carry;
    }
    __syncthreads();
    if (t < nb) rowptr[nbase + t] = ebeg + excl[t];
    if (b == NBUCK - 1 && t == 0) rowptr[NN] = ebeg + excl[nb];
    for (int i = ebeg + t; i < eend; i += 256) {
        int2 ed = bucketA[i];
        int dl = ed.y - nbase;
        int pos = atomicAdd(&cur[dl], 1);
        slot[ebeg + excl[dl] + pos] = ed.x;
    }
}

// ---------------- fused GAT gather: one wave per destination, single pass ----------------
__global__ __launch_bounds__(256) void edge_kernel(const bf16* __restrict__ Hb,
                                                   const float* __restrict__ AS,
                                                   const float* __restrict__ AD,
                                                   const int* __restrict__ rowptr,
                                                   const int* __restrict__ slot,
                                                   const float* __restrict__ bias,
                                                   float* __restrict__ OUT,
                                                   int relu_flag) {
    int wid = (blockIdx.x * 256 + threadIdx.x) >> 6;
    int lane = threadIdx.x & 63;
    if (wid >= NN) return;
    const int beg = rowptr[wid], end = rowptr[wid + 1];
    const float ad = AD[wid];
    float acc0 = 0.f, acc1 = 0.f, acc2 = 0.f, acc3 = 0.f, dsum = 0.f;
    for (int cbeg = beg; cbeg < end; cbeg += 64) {
        int j = cbeg + lane;
        float ex = 0.f; int s = 0;
        if (j < end) {
            s = slot[j];
            float e = AS[s] + ad;                 // AS gather: 400 KB, L2-resident
            e = e > 0.f ? e : 0.2f * e;
            ex = __expf(e);
            dsum += ex;
        }
        int cn = min(64, end - cbeg);
        int u = 0;
        for (; u + 4 <= cn; u += 4) {
            int s0 = __shfl(s, u),     s1 = __shfl(s, u + 1);
            int s2 = __shfl(s, u + 2), s3 = __shfl(s, u + 3);
            float e0 = __shfl(ex, u),     e1 = __shfl(ex, u + 1);
            float e2 = __shfl(ex, u + 2), e3 = __shfl(ex, u + 3);
            float h0 = __bfloat162float(Hb[(size_t)s0 * HID + lane]);
            float h1 = __bfloat162float(Hb[(size_t)s1 * HID + lane]);
            float h2 = __bfloat162float(Hb[(size_t)s2 * HID + lane]);
            float h3 = __bfloat162float(Hb[(size_t)s3 * HID + lane]);
            acc0 += e0 * h0; acc1 += e1 * h1; acc2 += e2 * h2; acc3 += e3 * h3;
        }
        for (; u < cn; ++u) {
            int su = __shfl(s, u);
            float eu = __shfl(ex, u);
            acc0 += eu * __bfloat162float(Hb[(size_t)su * HID + lane]);
        }
    }
#pragma unroll
    for (int off = 32; off; off >>= 1) dsum += __shfl_xor(dsum, off);
    float o = (acc0 + acc1 + acc2 + acc3) / dsum + bias[lane];
    if (relu_flag) o = fmaxf(o, 0.f);
    OUT[(size_t)wid * HID + lane] = o;
}

// ---------------- pooling: graph bounds + per-graph block mean ----------------
__global__ __launch_bounds__(256) void bounds_kernel(const int* __restrict__ bat,
                                                     const int* __restrict__ flags,
                                                     int* __restrict__ gstart) {
    int g = threadIdx.x;
    if (g > NG) return;
    const int i64 = flags[1];
    int lo = 0, hi = NN;
    while (lo < hi) {                       // first i with bat[i] >= g
        int mid = (lo + hi) >> 1;
        int v = i64 ? bat[2 * (long)mid] : bat[mid];
        if (v < g) lo = mid + 1; else hi = mid;
    }
    gstart[g] = lo;
}

__global__ __launch_bounds__(256) void pool2_kernel(const float* __restrict__ O,
                                                    const int* __restrict__ gstart,
                                                    float* __restrict__ pooled) {
    const int g = blockIdx.x;
    const int lane = threadIdx.x & 63;
    const int wv = threadIdx.x >> 6;
    const int beg = gstart[g], end = gstart[g + 1];
    float acc = 0.f;
    for (int i = beg + wv; i < end; i += 4)
        acc += O[(size_t)i * HID + lane];
    __shared__ float red[4][64];
    red[wv][lane] = acc;
    __syncthreads();
    if (wv == 0) {
        float s = red[0][lane] + red[1][lane] + red[2][lane] + red[3][lane];
        float cntg = (float)(end - beg);
        pooled[g * HID + lane] = s / fmaxf(cntg, 1.f);   // fused mean
    }
}

// ---------------- head: one block per graph, LDS staging ----------------
__global__ __launch_bounds__(64) void head_kernel(const float* __restrict__ pooled,
                                                  const float* __restrict__ lw, const float* __restrict__ lb,
                                                  const float* __restrict__ cw, const float* __restrict__ cb,
                                                  float* __restrict__ out) {
    const int g = blockIdx.x;
    const int t = threadIdx.x;
    __shared__ float p[HID];
    __shared__ float z[32];
    __shared__ float lg[NC];
    p[t] = pooled[g * HID + t];
    __syncthreads();
    if (t < 32) {
        float acc = lb[t];
#pragma unroll
        for (int k = 0; k < HID; k++) acc += p[k] * lw[k * 32 + t];
        z[t] = fmaxf(acc, 0.f);
    }
    __syncthreads();
    if (t < NC) {
        float acc = cb[t];
#pragma unroll
        for (int j = 0; j < 32; j++) acc += z[j] * cw[j * NC + t];
        lg[t] = acc;
    }
    __syncthreads();
    if (t < NC) {
        float mx = -1e30f;
#pragma unroll
        for (int c = 0; c < NC; c++) mx = fmaxf(mx, lg[c]);
        float s = 0.f;
#pragma unroll
        for (int c = 0; c < NC; c++) s += __expf(lg[c] - mx);
        out[g * NC + t] = lg[t] - mx - __logf(s);
    }
}

extern "C" void kernel_launch(void* const* d_in, const int* in_sizes, int n_in,
                              void* d_out, int out_size, void* d_ws, size_t ws_size,
                              hipStream_t stream) {
    const void* x   = d_in[0];
    const int*  ei  = (const int*)d_in[1];
    // d_in[2] edge_weight: unused (GATConv has no lin_edge)
    const int*  bat = (const int*)d_in[3];

    char* w = (char*)d_ws;
    int2* bucketA = (int2*)w;  w += sizeof(int2) * NT;        // 8-aligned first
    bf16* Hb      = (bf16*)w;  w += sizeof(bf16) * NN * HID;
    float* O      = (float*)w; w += sizeof(float) * NN * HID;
    float* AS     = (float*)w; w += sizeof(float) * NN;
    float* AD     = (float*)w; w += sizeof(float) * NN;
    int* rowptr   = (int*)w;   w += sizeof(int) * (NN + 1);
    int* slot     = (int*)w;   w += sizeof(int) * NT;
    float* pooled = (float*)w; w += sizeof(float) * NG * HID;
    int* gstart   = (int*)w;   w += sizeof(int) * (NG + 1);
    int* gcnt     = (int*)w;   w += sizeof(int) * NBUCK;
    int* gbase    = (int*)w;   w += sizeof(int) * (NBUCK + 1);
    int* gcursor  = (int*)w;   w += sizeof(int) * NBUCK;
    int* flags    = (int*)w;   w += sizeof(int) * 2;
    float* Pf     = (float*)w; w += sizeof(float) * 16384;

    // Pf offsets
    float* W1f = Pf;             float* as1 = Pf + 8192;
    float* ad1 = Pf + 8256;      float* b1  = Pf + 8320;
    float* W2f = Pf + 8384;      float* as2 = Pf + 12480;
    float* ad2 = Pf + 12544;     float* b2  = Pf + 12608;
    float* lw  = Pf + 12672;     float* lb  = Pf + 14720;
    float* cw  = Pf + 14752;     float* cb  = Pf + 15072;

    hipMemsetAsync(gcnt, 0, sizeof(int) * NBUCK, stream);

    probe_kernel<<<1, 64, 0, stream>>>((const unsigned int*)x, ei, flags);
    cparams_kernel<<<1, 256, 0, stream>>>(d_in[4], d_in[5], d_in[6], d_in[7],
                                          d_in[8], d_in[9], d_in[10], d_in[11],
                                          d_in[12], d_in[13], d_in[14], d_in[15],
                                          flags, Pf);
    // bucket CSR build
    bhistA_kernel<<<(NT + 8191) / 8192, 256, 0, stream>>>(ei, flags, gcnt);
    bscan_kernel<<<1, 64, 0, stream>>>(gcnt, gbase, gcursor);
    bscat_kernel<<<(NT + A2_EPB - 1) / A2_EPB, 256, 0, stream>>>(ei, flags, gcursor, bucketA);
    csr_kernel<<<NBUCK, 256, 0, stream>>>(bucketA, gbase, rowptr, slot);
    // layer 1
    gemm_kernel<FIN><<<NN / 16, 256, 0, stream>>>(x, W1f, Hb, flags, 0);
    alpha_kernel<<<NN / 4, 256, 0, stream>>>(Hb, as1, ad1, AS, AD);
    edge_kernel<<<NN / 4, 256, 0, stream>>>(Hb, AS, AD, rowptr, slot, b1, O, 1);
    // layer 2
    gemm_kernel<HID><<<NN / 16, 256, 0, stream>>>(O, W2f, Hb, flags, 1);
    alpha_kernel<<<NN / 4, 256, 0, stream>>>(Hb, as2, ad2, AS, AD);
    edge_kernel<<<NN / 4, 256, 0, stream>>>(Hb, AS, AD, rowptr, slot, b2, O, 0);
    // readout
    bounds_kernel<<<1, 256, 0, stream>>>(bat, flags, gstart);
    pool2_kernel<<<NG, 256, 0, stream>>>(O, gstart, pooled);
    head_kernel<<<NG, 64, 0, stream>>>(pooled, lw, lb, cw, cb, (float*)d_out);
}